// Round 1
// baseline (2385.916 us; speedup 1.0000x reference)
//
#include <hip/hip_runtime.h>
#include <math.h>

#define EPSV 1e-5f
#define NEGV -9e15f
#define HD 128
#define ITILE 32
#define JTILE 32
#define CCH 16

// ---------------- normalization scale kernels ----------------

// partial column sums of A over o: s1p[(b*CCH+c)*NV + v] = sum_{o in chunk c} A[b,o,v]
__global__ void colsum_part_k(const float* __restrict__ A, float* __restrict__ s1p,
                              int B, int NO, int NV) {
    int v = blockIdx.x * 256 + threadIdx.x;
    int c = blockIdx.y, b = blockIdx.z;
    if (v >= NV) return;
    int chunk = (NO + CCH - 1) / CCH;
    int o0 = c * chunk;
    int o1 = o0 + chunk; if (o1 > NO) o1 = NO;
    const float* Ab = A + (size_t)b * NO * NV + v;
    float s = 0.f;
    for (int o = o0; o < o1; ++o) s += Ab[(size_t)o * NV];
    s1p[((size_t)b * CCH + c) * NV + v] = s;
}

// rs1[b*NV+v] = 1/(sum_c s1p + EPS)
__global__ void colsum_fin_k(const float* __restrict__ s1p, float* __restrict__ rs1,
                             int B, int NV) {
    int idx = blockIdx.x * 256 + threadIdx.x;
    if (idx >= B * NV) return;
    int b = idx / NV, v = idx - b * NV;
    float s = 0.f;
    for (int c = 0; c < CCH; ++c) s += s1p[((size_t)b * CCH + c) * NV + v];
    rs1[idx] = 1.f / (s + EPSV);
}

// rs2[b*NO+o] = 1/(sum_v A[b,o,v]*rs1[b,v] + EPS), one wave per row
__global__ void rowsum_inv_k(const float* __restrict__ A, const float* __restrict__ rs1,
                             float* __restrict__ rs2, int B, int NO, int NV) {
    int row = blockIdx.x * (blockDim.x >> 6) + (threadIdx.x >> 6);
    int lane = threadIdx.x & 63;
    if (row >= B * NO) return;
    int b = row / NO;
    const float* Ar = A + (size_t)row * NV;
    const float* r1 = rs1 + (size_t)b * NV;
    float s = 0.f;
    for (int v = lane; v < NV; v += 64) s += Ar[v] * r1[v];
    for (int off = 32; off; off >>= 1) s += __shfl_xor(s, off, 64);
    if (lane == 0) rs2[row] = 1.f / (s + EPSV);
}

// ---------------- generic linear: out = act(X@W + bias + res) ----------------
// block 128 threads, 4 rows per block; thread handles channels c0 and c0+half.
template<int RELU, int BIAS, int RES>
__global__ __launch_bounds__(128)
void linear_k(const float* __restrict__ X, const float* __restrict__ W,
              const float* __restrict__ bias, const float* __restrict__ res,
              float* __restrict__ out, int rows, int K, int Dout) {
    __shared__ float xs[4][512];
    int row0 = blockIdx.x * 4;
    int t = threadIdx.x;
    int K4 = K >> 2;
    for (int l = t; l < 4 * K4; l += 128) {
        int r = l / K4, c4 = l - r * K4;
        float4 val = make_float4(0.f, 0.f, 0.f, 0.f);
        if (row0 + r < rows) val = ((const float4*)(X + (size_t)(row0 + r) * K))[c4];
        ((float4*)&xs[r][0])[c4] = val;
    }
    __syncthreads();
    int chunk = Dout < 256 ? Dout : 256;
    int half = chunk >> 1;
    if (t >= half) return;
    int c0 = blockIdx.y * chunk + t;
    int c1 = c0 + half;
    float a00 = 0, a01 = 0, a02 = 0, a03 = 0, a10 = 0, a11 = 0, a12 = 0, a13 = 0;
#pragma unroll 4
    for (int k = 0; k < K; ++k) {
        float w0 = W[(size_t)k * Dout + c0];
        float w1 = W[(size_t)k * Dout + c1];
        float x0 = xs[0][k], x1 = xs[1][k], x2 = xs[2][k], x3 = xs[3][k];
        a00 = fmaf(x0, w0, a00); a01 = fmaf(x1, w0, a01);
        a02 = fmaf(x2, w0, a02); a03 = fmaf(x3, w0, a03);
        a10 = fmaf(x0, w1, a10); a11 = fmaf(x1, w1, a11);
        a12 = fmaf(x2, w1, a12); a13 = fmaf(x3, w1, a13);
    }
    float accs[2][4] = {{a00, a01, a02, a03}, {a10, a11, a12, a13}};
    int cs[2] = {c0, c1};
    for (int h = 0; h < 2; ++h) {
        float bv = BIAS ? bias[cs[h]] : 0.f;
        for (int r = 0; r < 4; ++r) {
            int row = row0 + r;
            if (row >= rows) continue;
            float v = accs[h][r] + bv;
            if (RES) v += res[(size_t)row * Dout + cs[h]];
            if (RELU) v = fmaxf(v, 0.f);
            out[(size_t)row * Dout + cs[h]] = v;
        }
    }
}

// ---------------- GAT score vectors: sa = h.a1, sb = h.a2 ----------------
__global__ __launch_bounds__(128)
void scores_k(const float* __restrict__ h, const float* __restrict__ a1,
              const float* __restrict__ a2, float* __restrict__ sa,
              float* __restrict__ sb, int rows) {
    __shared__ float red1[128], red2[128];
    int row = blockIdx.x, t = threadIdx.x;
    float hv = h[(size_t)row * HD + t];
    red1[t] = hv * a1[t];
    red2[t] = hv * a2[t];
    __syncthreads();
    for (int s = 64; s; s >>= 1) {
        if (t < s) { red1[t] += red1[t + s]; red2[t] += red2[t + s]; }
        __syncthreads();
    }
    if (t == 0) { sa[row] = red1[0]; sb[row] = red2[0]; }
}

// ---------------- GAT softmax stats (online, one wave per row) ----------------
__global__ void gat_stats_k(const float* __restrict__ adj, const float* __restrict__ sa,
                            const float* __restrict__ sb, float* __restrict__ mrow,
                            float* __restrict__ rz, int B, int N) {
    int row = blockIdx.x * (blockDim.x >> 6) + (threadIdx.x >> 6);
    int lane = threadIdx.x & 63;
    if (row >= B * N) return;
    int b = row / N;
    const float* arow = adj + (size_t)row * N;
    const float* sbb = sb + (size_t)b * N;
    float si = sa[row];
    float m = -INFINITY, Z = 0.f;
    for (int j = lane; j < N; j += 64) {
        float e = si + sbb[j];
        e = e > 0.f ? e : 0.2f * e;
        e = arow[j] > 0.f ? e : NEGV;
        if (e > m) { Z = Z * expf(m - e) + 1.f; m = e; }
        else       { Z += expf(e - m); }
    }
    for (int off = 32; off; off >>= 1) {
        float mo = __shfl_xor(m, off, 64);
        float Zo = __shfl_xor(Z, off, 64);
        float mn = fmaxf(m, mo);
        Z = Z * expf(m - mn) + Zo * expf(mo - mn);
        m = mn;
    }
    if (lane == 0) { mrow[row] = m; rz[row] = 1.f / Z; }
}

// ---------------- shared tile FMA: 4 rows x 8 channels per thread ----------------
__device__ __forceinline__ void tile_fma(const float (*hs)[HD], const float (*ws)[JTILE + 1],
                                         int slot, int c0, float acc[4][8]) {
#pragma unroll 8
    for (int jl = 0; jl < JTILE; ++jl) {
        float4 h0 = *(const float4*)&hs[jl][c0];
        float4 h1 = *(const float4*)&hs[jl][c0 + 64];
#pragma unroll
        for (int q = 0; q < 4; ++q) {
            float w = ws[slot * 4 + q][jl];
            acc[q][0] = fmaf(w, h0.x, acc[q][0]);
            acc[q][1] = fmaf(w, h0.y, acc[q][1]);
            acc[q][2] = fmaf(w, h0.z, acc[q][2]);
            acc[q][3] = fmaf(w, h0.w, acc[q][3]);
            acc[q][4] = fmaf(w, h1.x, acc[q][4]);
            acc[q][5] = fmaf(w, h1.y, acc[q][5]);
            acc[q][6] = fmaf(w, h1.z, acc[q][6]);
            acc[q][7] = fmaf(w, h1.w, acc[q][7]);
        }
    }
}

// ---------------- GAT aggregation: out = relu(softmax(att) @ h) ----------------
__global__ __launch_bounds__(128)
void gat_agg_k(const float* __restrict__ adj, const float* __restrict__ h,
               const float* __restrict__ sa, const float* __restrict__ sb,
               const float* __restrict__ mrow, const float* __restrict__ rz,
               float* __restrict__ out, int B, int N) {
    __shared__ float hs[JTILE][HD];
    __shared__ float ws[ITILE][JTILE + 1];
    __shared__ float sa_s[ITILE], m_s[ITILE];
    int tilesPerB = (N + ITILE - 1) / ITILE;
    int b = blockIdx.x / tilesPerB;
    int i0 = (blockIdx.x - b * tilesPerB) * ITILE;
    int t = threadIdx.x;
    if (t < ITILE) {
        int i = i0 + t;
        sa_s[t] = (i < N) ? sa[(size_t)b * N + i] : 0.f;
        m_s[t]  = (i < N) ? mrow[(size_t)b * N + i] : 0.f;
    }
    int slot = t >> 4, c0 = (t & 15) * 4;
    float acc[4][8];
#pragma unroll
    for (int q = 0; q < 4; ++q)
#pragma unroll
        for (int x = 0; x < 8; ++x) acc[q][x] = 0.f;
    const float* adjb = adj + ((size_t)b * N + i0) * N;
    const float* hb = h + (size_t)b * N * HD;
    const float* sbb = sb + (size_t)b * N;
    __syncthreads();
    for (int j0 = 0; j0 < N; j0 += JTILE) {
        for (int l = t; l < JTILE * (HD / 4); l += 128) {
            int jj = l >> 5, c4 = l & 31;
            int j = j0 + jj;
            float4 val = make_float4(0.f, 0.f, 0.f, 0.f);
            if (j < N) val = ((const float4*)&hb[(size_t)j * HD])[c4];
            ((float4*)&hs[jj][0])[c4] = val;
        }
        for (int l = t; l < ITILE * JTILE; l += 128) {
            int il = l >> 5, jl = l & 31;
            int i = i0 + il, j = j0 + jl;
            float w = 0.f;
            if (i < N && j < N) {
                float e = sa_s[il] + sbb[j];
                e = e > 0.f ? e : 0.2f * e;
                e = adjb[(size_t)il * N + j] > 0.f ? e : NEGV;
                w = expf(e - m_s[il]);
            }
            ws[il][jl] = w;
        }
        __syncthreads();
        tile_fma(hs, ws, slot, c0, acc);
        __syncthreads();
    }
#pragma unroll
    for (int q = 0; q < 4; ++q) {
        int i = i0 + slot * 4 + q;
        if (i >= N) continue;
        float r = rz[(size_t)b * N + i];
        float* op = out + ((size_t)b * N + i) * HD;
#pragma unroll
        for (int x = 0; x < 4; ++x) op[c0 + x]      = fmaxf(acc[q][x] * r, 0.f);
#pragma unroll
        for (int x = 0; x < 4; ++x) op[c0 + 64 + x] = fmaxf(acc[q][4 + x] * r, 0.f);
    }
}

// ---------------- cross vo: out[b,v,c] = rs1[b,v] * sum_o A[b,o,v]*src[b,o,c] ----------------
__global__ __launch_bounds__(128)
void cross_vo_k(const float* __restrict__ A, const float* __restrict__ src,
                const float* __restrict__ rs1, float* __restrict__ out,
                int B, int NO, int NV) {
    __shared__ float hs[JTILE][HD];
    __shared__ float ws[ITILE][JTILE + 1];
    int tilesPerB = (NV + ITILE - 1) / ITILE;
    int b = blockIdx.x / tilesPerB;
    int i0 = (blockIdx.x - b * tilesPerB) * ITILE;
    int t = threadIdx.x;
    int slot = t >> 4, c0 = (t & 15) * 4;
    float acc[4][8];
#pragma unroll
    for (int q = 0; q < 4; ++q)
#pragma unroll
        for (int x = 0; x < 8; ++x) acc[q][x] = 0.f;
    const float* Ab = A + (size_t)b * NO * NV;
    const float* sb_ = src + (size_t)b * NO * HD;
    for (int j0 = 0; j0 < NO; j0 += JTILE) {
        for (int l = t; l < JTILE * (HD / 4); l += 128) {
            int jj = l >> 5, c4 = l & 31;
            int j = j0 + jj;
            float4 val = make_float4(0.f, 0.f, 0.f, 0.f);
            if (j < NO) val = ((const float4*)&sb_[(size_t)j * HD])[c4];
            ((float4*)&hs[jj][0])[c4] = val;
        }
        for (int l = t; l < ITILE * JTILE; l += 128) {
            int il = l & 31, jl = l >> 5;   // consecutive t -> consecutive v (coalesced)
            int v = i0 + il, o = j0 + jl;
            ws[il][jl] = (v < NV && o < NO) ? Ab[(size_t)o * NV + v] : 0.f;
        }
        __syncthreads();
        tile_fma(hs, ws, slot, c0, acc);
        __syncthreads();
    }
#pragma unroll
    for (int q = 0; q < 4; ++q) {
        int i = i0 + slot * 4 + q;
        if (i >= NV) continue;
        float r = rs1[(size_t)b * NV + i];
        float* op = out + ((size_t)b * NV + i) * HD;
#pragma unroll
        for (int x = 0; x < 4; ++x) op[c0 + x]      = acc[q][x] * r;
#pragma unroll
        for (int x = 0; x < 4; ++x) op[c0 + 64 + x] = acc[q][4 + x] * r;
    }
}

// ---------------- cross ov: out[b,o,c] = rs2[b,o] * sum_v A[b,o,v]*rs1[b,v]*src[b,v,c] --------
__global__ __launch_bounds__(128)
void cross_ov_k(const float* __restrict__ A, const float* __restrict__ src,
                const float* __restrict__ rs1, const float* __restrict__ rs2,
                float* __restrict__ out, int B, int NO, int NV) {
    __shared__ float hs[JTILE][HD];
    __shared__ float ws[ITILE][JTILE + 1];
    int tilesPerB = (NO + ITILE - 1) / ITILE;
    int b = blockIdx.x / tilesPerB;
    int i0 = (blockIdx.x - b * tilesPerB) * ITILE;
    int t = threadIdx.x;
    int slot = t >> 4, c0 = (t & 15) * 4;
    float acc[4][8];
#pragma unroll
    for (int q = 0; q < 4; ++q)
#pragma unroll
        for (int x = 0; x < 8; ++x) acc[q][x] = 0.f;
    const float* Ab = A + (size_t)b * NO * NV;
    const float* sb_ = src + (size_t)b * NV * HD;
    const float* r1b = rs1 + (size_t)b * NV;
    for (int j0 = 0; j0 < NV; j0 += JTILE) {
        for (int l = t; l < JTILE * (HD / 4); l += 128) {
            int jj = l >> 5, c4 = l & 31;
            int j = j0 + jj;
            float4 val = make_float4(0.f, 0.f, 0.f, 0.f);
            if (j < NV) {
                val = ((const float4*)&sb_[(size_t)j * HD])[c4];
                float sc = r1b[j];
                val.x *= sc; val.y *= sc; val.z *= sc; val.w *= sc;
            }
            ((float4*)&hs[jj][0])[c4] = val;
        }
        for (int l = t; l < ITILE * JTILE; l += 128) {
            int il = l >> 5, jl = l & 31;  // consecutive t -> consecutive v (coalesced)
            int o = i0 + il, v = j0 + jl;
            ws[il][jl] = (o < NO && v < NV) ? Ab[(size_t)o * NV + v] : 0.f;
        }
        __syncthreads();
        tile_fma(hs, ws, slot, c0, acc);
        __syncthreads();
    }
#pragma unroll
    for (int q = 0; q < 4; ++q) {
        int i = i0 + slot * 4 + q;
        if (i >= NO) continue;
        float r = rs2[(size_t)b * NO + i];
        float* op = out + ((size_t)b * NO + i) * HD;
#pragma unroll
        for (int x = 0; x < 4; ++x) op[c0 + x]      = acc[q][x] * r;
#pragma unroll
        for (int x = 0; x < 4; ++x) op[c0 + 64 + x] = acc[q][4 + x] * r;
    }
}

// ---------------- host launcher ----------------
extern "C" void kernel_launch(void* const* d_in, const int* in_sizes, int n_in,
                              void* d_out, int out_size, void* d_ws, size_t ws_size,
                              hipStream_t stream) {
    const int B = 8, NV = 500, NO = 1500, DV = 512, DO = 32;
    const float* vis_memory = (const float*)d_in[0];
    const float* obj_memory = (const float*)d_in[1];
    const float* vis_adj    = (const float*)d_in[2];
    const float* obj_adj    = (const float*)d_in[3];
    const float* A_OV       = (const float*)d_in[4];
    const float* Wv1  = (const float*)d_in[5];
    const float* av1a = (const float*)d_in[6];
    const float* av1b = (const float*)d_in[7];
    const float* Wv2  = (const float*)d_in[8];
    const float* av2a = (const float*)d_in[9];
    const float* av2b = (const float*)d_in[10];
    const float* Wo1  = (const float*)d_in[11];
    const float* ao1a = (const float*)d_in[12];
    const float* ao1b = (const float*)d_in[13];
    const float* Wo2  = (const float*)d_in[14];
    const float* ao2a = (const float*)d_in[15];
    const float* ao2b = (const float*)d_in[16];
    const float* g2o_W1 = (const float*)d_in[17];
    const float* g2o_b1 = (const float*)d_in[18];
    const float* g2o_W2 = (const float*)d_in[19];
    const float* g2o_b2 = (const float*)d_in[20];
    const float* o2g_W1 = (const float*)d_in[21];
    const float* o2g_b1 = (const float*)d_in[22];
    const float* o2g_W2 = (const float*)d_in[23];
    const float* o2g_b2 = (const float*)d_in[24];
    const float* img_W = (const float*)d_in[25];
    const float* img_b = (const float*)d_in[26];
    const float* obj_W = (const float*)d_in[27];
    const float* obj_b = (const float*)d_in[28];

    float* wsp = (float*)d_ws;
    size_t off = 0;
    auto alloc = [&](size_t n) { float* p = wsp + off; off += n; return p; };
    float* rs1  = alloc(B * NV);
    float* rs2  = alloc(B * NO);
    float* sa   = alloc(B * NO);
    float* sbv  = alloc(B * NO);
    float* mr   = alloc(B * NO);
    float* rz   = alloc(B * NO);
    float* s1p  = alloc((size_t)B * CCH * NV);
    float* hv   = alloc((size_t)B * NV * HD);
    float* ho   = alloc((size_t)B * NO * HD);
    float* v1   = alloc((size_t)B * NV * HD);
    float* o1   = alloc((size_t)B * NO * HD);
    float* visb = alloc((size_t)B * NV * HD);
    float* objb = alloc((size_t)B * NO * HD);
    float* cv   = alloc((size_t)B * NV * HD);
    float* co   = alloc((size_t)B * NO * HD);
    float* tmp  = alloc((size_t)B * NO * HD);

    // normalization scales
    colsum_part_k<<<dim3((NV + 255) / 256, CCH, B), 256, 0, stream>>>(A_OV, s1p, B, NO, NV);
    colsum_fin_k<<<dim3((B * NV + 255) / 256), 256, 0, stream>>>(s1p, rs1, B, NV);
    rowsum_inv_k<<<dim3((B * NO + 3) / 4), 256, 0, stream>>>(A_OV, rs1, rs2, B, NO, NV);

    const int vtiles = (NV + ITILE - 1) / ITILE;
    const int otiles = (NO + ITILE - 1) / ITILE;

    auto gat = [&](const float* X, int N, int K, const float* W, const float* a1,
                   const float* a2, const float* adj, float* hbuf, float* outbuf) {
        linear_k<0, 0, 0><<<dim3((B * N + 3) / 4, 1), 128, 0, stream>>>(
            X, W, nullptr, nullptr, hbuf, B * N, K, HD);
        scores_k<<<dim3(B * N), 128, 0, stream>>>(hbuf, a1, a2, sa, sbv, B * N);
        gat_stats_k<<<dim3((B * N + 3) / 4), 256, 0, stream>>>(adj, sa, sbv, mr, rz, B, N);
        int tiles = (N + ITILE - 1) / ITILE;
        gat_agg_k<<<dim3(B * tiles), 128, 0, stream>>>(adj, hbuf, sa, sbv, mr, rz, outbuf, B, N);
    };

    auto cross_and_mlp = [&](const float* vsrc, const float* osrc, float* visout, float* objout) {
        // vis branch: visout = vsrc + mlp(vo @ osrc; o2g)
        cross_vo_k<<<dim3(B * vtiles), 128, 0, stream>>>(A_OV, osrc, rs1, cv, B, NO, NV);
        linear_k<1, 1, 0><<<dim3((B * NV + 3) / 4, 1), 128, 0, stream>>>(
            cv, o2g_W1, o2g_b1, nullptr, tmp, B * NV, HD, HD);
        linear_k<0, 1, 1><<<dim3((B * NV + 3) / 4, 1), 128, 0, stream>>>(
            tmp, o2g_W2, o2g_b2, vsrc, visout, B * NV, HD, HD);
        // obj branch: objout = osrc + mlp(ov @ vsrc; g2o)
        cross_ov_k<<<dim3(B * otiles), 128, 0, stream>>>(A_OV, vsrc, rs1, rs2, co, B, NO, NV);
        linear_k<1, 1, 0><<<dim3((B * NO + 3) / 4, 1), 128, 0, stream>>>(
            co, g2o_W1, g2o_b1, nullptr, tmp, B * NO, HD, HD);
        linear_k<0, 1, 1><<<dim3((B * NO + 3) / 4, 1), 128, 0, stream>>>(
            tmp, g2o_W2, g2o_b2, osrc, objout, B * NO, HD, HD);
    };

    // layer 1
    gat(vis_memory, NV, DV, Wv1, av1a, av1b, vis_adj, hv, v1);
    gat(obj_memory, NO, DO, Wo1, ao1a, ao1b, obj_adj, ho, o1);
    cross_and_mlp(v1, o1, visb, objb);

    // layer 2 (v2 -> v1 buffer, o2 -> o1 buffer)
    gat(visb, NV, HD, Wv2, av2a, av2b, vis_adj, hv, v1);
    gat(objb, NO, HD, Wo2, ao2a, ao2b, obj_adj, ho, o1);
    cross_and_mlp(v1, o1, visb, objb);

    // output projections
    float* vis_out = (float*)d_out;
    float* obj_out = vis_out + (size_t)B * NV * DV;
    linear_k<0, 1, 0><<<dim3((B * NV + 3) / 4, (DV + 255) / 256), 128, 0, stream>>>(
        visb, img_W, img_b, nullptr, vis_out, B * NV, HD, DV);
    linear_k<0, 1, 0><<<dim3((B * NO + 3) / 4, 1), 128, 0, stream>>>(
        objb, obj_W, obj_b, nullptr, obj_out, B * NO, HD, DO);
}

// Round 2
// 1754.538 us; speedup vs baseline: 1.3599x; 1.3599x over previous
//
#include <hip/hip_runtime.h>
#include <math.h>

#define EPSV 1e-5f
#define NEGV -9e15f
#define HD 128
#define ITILE 32
#define JTILE 32
#define CCH 16
#define SPLIT 8

// ---------------- normalization scale kernels ----------------

__global__ void colsum_part_k(const float* __restrict__ A, float* __restrict__ s1p,
                              int B, int NO, int NV) {
    int v = blockIdx.x * 256 + threadIdx.x;
    int c = blockIdx.y, b = blockIdx.z;
    if (v >= NV) return;
    int chunk = (NO + CCH - 1) / CCH;
    int o0 = c * chunk;
    int o1 = o0 + chunk; if (o1 > NO) o1 = NO;
    const float* Ab = A + (size_t)b * NO * NV + v;
    float s = 0.f;
    for (int o = o0; o < o1; ++o) s += Ab[(size_t)o * NV];
    s1p[((size_t)b * CCH + c) * NV + v] = s;
}

__global__ void colsum_fin_k(const float* __restrict__ s1p, float* __restrict__ rs1,
                             int B, int NV) {
    int idx = blockIdx.x * 256 + threadIdx.x;
    if (idx >= B * NV) return;
    int b = idx / NV, v = idx - b * NV;
    float s = 0.f;
    for (int c = 0; c < CCH; ++c) s += s1p[((size_t)b * CCH + c) * NV + v];
    rs1[idx] = 1.f / (s + EPSV);
}

__global__ void rowsum_inv_k(const float* __restrict__ A, const float* __restrict__ rs1,
                             float* __restrict__ rs2, int B, int NO, int NV) {
    int row = blockIdx.x * (blockDim.x >> 6) + (threadIdx.x >> 6);
    int lane = threadIdx.x & 63;
    if (row >= B * NO) return;
    int b = row / NO;
    const float* Ar = A + (size_t)row * NV;
    const float* r1 = rs1 + (size_t)b * NV;
    float s = 0.f;
    for (int v = lane; v < NV; v += 64) s += Ar[v] * r1[v];
    for (int off = 32; off; off >>= 1) s += __shfl_xor(s, off, 64);
    if (lane == 0) rs2[row] = 1.f / (s + EPSV);
}

// ---------------- generic linear: out = act(X@W + bias + res) ----------------
template<int RELU, int BIAS, int RES>
__global__ __launch_bounds__(128)
void linear_k(const float* __restrict__ X, const float* __restrict__ W,
              const float* __restrict__ bias, const float* __restrict__ res,
              float* __restrict__ out, int rows, int K, int Dout) {
    __shared__ float xs[4][512];
    int row0 = blockIdx.x * 4;
    int t = threadIdx.x;
    int K4 = K >> 2;
    for (int l = t; l < 4 * K4; l += 128) {
        int r = l / K4, c4 = l - r * K4;
        float4 val = make_float4(0.f, 0.f, 0.f, 0.f);
        if (row0 + r < rows) val = ((const float4*)(X + (size_t)(row0 + r) * K))[c4];
        ((float4*)&xs[r][0])[c4] = val;
    }
    __syncthreads();
    int chunk = Dout < 256 ? Dout : 256;
    int half = chunk >> 1;
    if (t >= half) return;
    int c0 = blockIdx.y * chunk + t;
    int c1 = c0 + half;
    float a00 = 0, a01 = 0, a02 = 0, a03 = 0, a10 = 0, a11 = 0, a12 = 0, a13 = 0;
#pragma unroll 4
    for (int k = 0; k < K; ++k) {
        float w0 = W[(size_t)k * Dout + c0];
        float w1 = W[(size_t)k * Dout + c1];
        float x0 = xs[0][k], x1 = xs[1][k], x2 = xs[2][k], x3 = xs[3][k];
        a00 = fmaf(x0, w0, a00); a01 = fmaf(x1, w0, a01);
        a02 = fmaf(x2, w0, a02); a03 = fmaf(x3, w0, a03);
        a10 = fmaf(x0, w1, a10); a11 = fmaf(x1, w1, a11);
        a12 = fmaf(x2, w1, a12); a13 = fmaf(x3, w1, a13);
    }
    float accs[2][4] = {{a00, a01, a02, a03}, {a10, a11, a12, a13}};
    int cs[2] = {c0, c1};
    for (int h = 0; h < 2; ++h) {
        float bv = BIAS ? bias[cs[h]] : 0.f;
        for (int r = 0; r < 4; ++r) {
            int row = row0 + r;
            if (row >= rows) continue;
            float v = accs[h][r] + bv;
            if (RES) v += res[(size_t)row * Dout + cs[h]];
            if (RELU) v = fmaxf(v, 0.f);
            out[(size_t)row * Dout + cs[h]] = v;
        }
    }
}

// ---------------- GAT score vectors ----------------
__global__ __launch_bounds__(128)
void scores_k(const float* __restrict__ h, const float* __restrict__ a1,
              const float* __restrict__ a2, float* __restrict__ sa,
              float* __restrict__ sb, int rows) {
    __shared__ float red1[128], red2[128];
    int row = blockIdx.x, t = threadIdx.x;
    float hv = h[(size_t)row * HD + t];
    red1[t] = hv * a1[t];
    red2[t] = hv * a2[t];
    __syncthreads();
    for (int s = 64; s; s >>= 1) {
        if (t < s) { red1[t] += red1[t + s]; red2[t] += red2[t + s]; }
        __syncthreads();
    }
    if (t == 0) { sa[row] = red1[0]; sb[row] = red2[0]; }
}

// ---------------- GAT softmax stats ----------------
__global__ void gat_stats_k(const float* __restrict__ adj, const float* __restrict__ sa,
                            const float* __restrict__ sb, float* __restrict__ mrow,
                            float* __restrict__ rz, int B, int N) {
    int row = blockIdx.x * (blockDim.x >> 6) + (threadIdx.x >> 6);
    int lane = threadIdx.x & 63;
    if (row >= B * N) return;
    int b = row / N;
    const float* arow = adj + (size_t)row * N;
    const float* sbb = sb + (size_t)b * N;
    float si = sa[row];
    float m = -INFINITY, Z = 0.f;
    for (int j = lane; j < N; j += 64) {
        float e = si + sbb[j];
        e = e > 0.f ? e : 0.2f * e;
        e = arow[j] > 0.f ? e : NEGV;
        if (e > m) { Z = Z * expf(m - e) + 1.f; m = e; }
        else       { Z += expf(e - m); }
    }
    for (int off = 32; off; off >>= 1) {
        float mo = __shfl_xor(m, off, 64);
        float Zo = __shfl_xor(Z, off, 64);
        float mn = fmaxf(m, mo);
        Z = Z * expf(m - mn) + Zo * expf(mo - mn);
        m = mn;
    }
    if (lane == 0) { mrow[row] = m; rz[row] = 1.f / Z; }
}

// ---------------- shared tile FMA ----------------
__device__ __forceinline__ void tile_fma(const float (*hs)[HD], const float (*ws)[JTILE + 1],
                                         int slot, int c0, float acc[4][8]) {
#pragma unroll 8
    for (int jl = 0; jl < JTILE; ++jl) {
        float4 h0 = *(const float4*)&hs[jl][c0];
        float4 h1 = *(const float4*)&hs[jl][c0 + 64];
#pragma unroll
        for (int q = 0; q < 4; ++q) {
            float w = ws[slot * 4 + q][jl];
            acc[q][0] = fmaf(w, h0.x, acc[q][0]);
            acc[q][1] = fmaf(w, h0.y, acc[q][1]);
            acc[q][2] = fmaf(w, h0.z, acc[q][2]);
            acc[q][3] = fmaf(w, h0.w, acc[q][3]);
            acc[q][4] = fmaf(w, h1.x, acc[q][4]);
            acc[q][5] = fmaf(w, h1.y, acc[q][5]);
            acc[q][6] = fmaf(w, h1.z, acc[q][6]);
            acc[q][7] = fmaf(w, h1.w, acc[q][7]);
        }
    }
}

__device__ __forceinline__ void acc_atomic_store(float* __restrict__ accout, size_t rowbase,
                                                 int i0, int N, int slot, int c0,
                                                 float acc[4][8]) {
#pragma unroll
    for (int q = 0; q < 4; ++q) {
        int i = i0 + slot * 4 + q;
        if (i >= N) continue;
        float* op = accout + rowbase + (size_t)i * HD;
#pragma unroll
        for (int x = 0; x < 4; ++x) atomicAdd(&op[c0 + x], acc[q][x]);
#pragma unroll
        for (int x = 0; x < 4; ++x) atomicAdd(&op[c0 + 64 + x], acc[q][4 + x]);
    }
}

// ---------------- GAT aggregation (j-split, atomic partial accumulate) ----------------
__global__ __launch_bounds__(128)
void gat_agg_k(const float* __restrict__ adj, const float* __restrict__ h,
               const float* __restrict__ sa, const float* __restrict__ sb,
               const float* __restrict__ mrow, float* __restrict__ accout,
               int B, int N, int tilesPerSplit) {
    __shared__ float hs[JTILE][HD];
    __shared__ float ws[ITILE][JTILE + 1];
    __shared__ float sa_s[ITILE], m_s[ITILE];
    int tilesPerB = (N + ITILE - 1) / ITILE;
    int b = blockIdx.x / tilesPerB;
    int i0 = (blockIdx.x - b * tilesPerB) * ITILE;
    int j_begin = blockIdx.y * tilesPerSplit * JTILE;
    if (j_begin >= N) return;
    int j_end = j_begin + tilesPerSplit * JTILE;
    if (j_end > N) j_end = N;
    int t = threadIdx.x;
    if (t < ITILE) {
        int i = i0 + t;
        sa_s[t] = (i < N) ? sa[(size_t)b * N + i] : 0.f;
        m_s[t]  = (i < N) ? mrow[(size_t)b * N + i] : 0.f;
    }
    int slot = t >> 4, c0 = (t & 15) * 4;
    float acc[4][8];
#pragma unroll
    for (int q = 0; q < 4; ++q)
#pragma unroll
        for (int x = 0; x < 8; ++x) acc[q][x] = 0.f;
    const float* adjb = adj + ((size_t)b * N + i0) * N;
    const float* hb = h + (size_t)b * N * HD;
    const float* sbb = sb + (size_t)b * N;
    __syncthreads();
    for (int j0 = j_begin; j0 < j_end; j0 += JTILE) {
        for (int l = t; l < JTILE * (HD / 4); l += 128) {
            int jj = l >> 5, c4 = l & 31;
            int j = j0 + jj;
            float4 val = make_float4(0.f, 0.f, 0.f, 0.f);
            if (j < N) val = ((const float4*)&hb[(size_t)j * HD])[c4];
            ((float4*)&hs[jj][0])[c4] = val;
        }
        for (int l = t; l < ITILE * JTILE; l += 128) {
            int il = l >> 5, jl = l & 31;
            int i = i0 + il, j = j0 + jl;
            float w = 0.f;
            if (i < N && j < N) {
                float e = sa_s[il] + sbb[j];
                e = e > 0.f ? e : 0.2f * e;
                e = adjb[(size_t)il * N + j] > 0.f ? e : NEGV;
                w = expf(e - m_s[il]);
            }
            ws[il][jl] = w;
        }
        __syncthreads();
        tile_fma(hs, ws, slot, c0, acc);
        __syncthreads();
    }
    acc_atomic_store(accout, (size_t)b * N * HD, i0, N, slot, c0, acc);
}

// ---------------- cross vo (j-split over NO) ----------------
__global__ __launch_bounds__(128)
void cross_vo_k(const float* __restrict__ A, const float* __restrict__ src,
                float* __restrict__ accout, int B, int NO, int NV, int tilesPerSplit) {
    __shared__ float hs[JTILE][HD];
    __shared__ float ws[ITILE][JTILE + 1];
    int tilesPerB = (NV + ITILE - 1) / ITILE;
    int b = blockIdx.x / tilesPerB;
    int i0 = (blockIdx.x - b * tilesPerB) * ITILE;
    int j_begin = blockIdx.y * tilesPerSplit * JTILE;
    if (j_begin >= NO) return;
    int j_end = j_begin + tilesPerSplit * JTILE;
    if (j_end > NO) j_end = NO;
    int t = threadIdx.x;
    int slot = t >> 4, c0 = (t & 15) * 4;
    float acc[4][8];
#pragma unroll
    for (int q = 0; q < 4; ++q)
#pragma unroll
        for (int x = 0; x < 8; ++x) acc[q][x] = 0.f;
    const float* Ab = A + (size_t)b * NO * NV;
    const float* sb_ = src + (size_t)b * NO * HD;
    for (int j0 = j_begin; j0 < j_end; j0 += JTILE) {
        for (int l = t; l < JTILE * (HD / 4); l += 128) {
            int jj = l >> 5, c4 = l & 31;
            int j = j0 + jj;
            float4 val = make_float4(0.f, 0.f, 0.f, 0.f);
            if (j < NO) val = ((const float4*)&sb_[(size_t)j * HD])[c4];
            ((float4*)&hs[jj][0])[c4] = val;
        }
        for (int l = t; l < ITILE * JTILE; l += 128) {
            int il = l & 31, jl = l >> 5;   // consecutive t -> consecutive v (coalesced)
            int v = i0 + il, o = j0 + jl;
            ws[il][jl] = (v < NV && o < NO) ? Ab[(size_t)o * NV + v] : 0.f;
        }
        __syncthreads();
        tile_fma(hs, ws, slot, c0, acc);
        __syncthreads();
    }
    acc_atomic_store(accout, (size_t)b * NV * HD, i0, NV, slot, c0, acc);
}

// ---------------- cross ov (j-split over NV) ----------------
__global__ __launch_bounds__(128)
void cross_ov_k(const float* __restrict__ A, const float* __restrict__ src,
                const float* __restrict__ rs1, float* __restrict__ accout,
                int B, int NO, int NV, int tilesPerSplit) {
    __shared__ float hs[JTILE][HD];
    __shared__ float ws[ITILE][JTILE + 1];
    int tilesPerB = (NO + ITILE - 1) / ITILE;
    int b = blockIdx.x / tilesPerB;
    int i0 = (blockIdx.x - b * tilesPerB) * ITILE;
    int j_begin = blockIdx.y * tilesPerSplit * JTILE;
    if (j_begin >= NV) return;
    int j_end = j_begin + tilesPerSplit * JTILE;
    if (j_end > NV) j_end = NV;
    int t = threadIdx.x;
    int slot = t >> 4, c0 = (t & 15) * 4;
    float acc[4][8];
#pragma unroll
    for (int q = 0; q < 4; ++q)
#pragma unroll
        for (int x = 0; x < 8; ++x) acc[q][x] = 0.f;
    const float* Ab = A + (size_t)b * NO * NV;
    const float* sb_ = src + (size_t)b * NV * HD;
    const float* r1b = rs1 + (size_t)b * NV;
    for (int j0 = j_begin; j0 < j_end; j0 += JTILE) {
        for (int l = t; l < JTILE * (HD / 4); l += 128) {
            int jj = l >> 5, c4 = l & 31;
            int j = j0 + jj;
            float4 val = make_float4(0.f, 0.f, 0.f, 0.f);
            if (j < NV) {
                val = ((const float4*)&sb_[(size_t)j * HD])[c4];
                float sc = r1b[j];
                val.x *= sc; val.y *= sc; val.z *= sc; val.w *= sc;
            }
            ((float4*)&hs[jj][0])[c4] = val;
        }
        for (int l = t; l < ITILE * JTILE; l += 128) {
            int il = l >> 5, jl = l & 31;  // consecutive t -> consecutive v (coalesced)
            int o = i0 + il, v = j0 + jl;
            ws[il][jl] = (o < NO && v < NV) ? Ab[(size_t)o * NV + v] : 0.f;
        }
        __syncthreads();
        tile_fma(hs, ws, slot, c0, acc);
        __syncthreads();
    }
    acc_atomic_store(accout, (size_t)b * NO * HD, i0, NO, slot, c0, acc);
}

// ---------------- finalize: out = maybe_relu(acc * scale[row]) ----------------
template<int RELU>
__global__ __launch_bounds__(256)
void finalize_k(const float* __restrict__ acc, const float* __restrict__ scale,
                float* __restrict__ out, int rows) {
    int idx = blockIdx.x * 256 + threadIdx.x;
    int total = rows * (HD / 4);
    if (idx >= total) return;
    int row = idx >> 5;                 // HD/4 == 32
    float4 v = ((const float4*)acc)[idx];
    float s = scale[row];
    v.x *= s; v.y *= s; v.z *= s; v.w *= s;
    if (RELU) {
        v.x = fmaxf(v.x, 0.f); v.y = fmaxf(v.y, 0.f);
        v.z = fmaxf(v.z, 0.f); v.w = fmaxf(v.w, 0.f);
    }
    ((float4*)out)[idx] = v;
}

// ---------------- host launcher ----------------
extern "C" void kernel_launch(void* const* d_in, const int* in_sizes, int n_in,
                              void* d_out, int out_size, void* d_ws, size_t ws_size,
                              hipStream_t stream) {
    const int B = 8, NV = 500, NO = 1500, DV = 512, DO = 32;
    const float* vis_memory = (const float*)d_in[0];
    const float* obj_memory = (const float*)d_in[1];
    const float* vis_adj    = (const float*)d_in[2];
    const float* obj_adj    = (const float*)d_in[3];
    const float* A_OV       = (const float*)d_in[4];
    const float* Wv1  = (const float*)d_in[5];
    const float* av1a = (const float*)d_in[6];
    const float* av1b = (const float*)d_in[7];
    const float* Wv2  = (const float*)d_in[8];
    const float* av2a = (const float*)d_in[9];
    const float* av2b = (const float*)d_in[10];
    const float* Wo1  = (const float*)d_in[11];
    const float* ao1a = (const float*)d_in[12];
    const float* ao1b = (const float*)d_in[13];
    const float* Wo2  = (const float*)d_in[14];
    const float* ao2a = (const float*)d_in[15];
    const float* ao2b = (const float*)d_in[16];
    const float* g2o_W1 = (const float*)d_in[17];
    const float* g2o_b1 = (const float*)d_in[18];
    const float* g2o_W2 = (const float*)d_in[19];
    const float* g2o_b2 = (const float*)d_in[20];
    const float* o2g_W1 = (const float*)d_in[21];
    const float* o2g_b1 = (const float*)d_in[22];
    const float* o2g_W2 = (const float*)d_in[23];
    const float* o2g_b2 = (const float*)d_in[24];
    const float* img_W = (const float*)d_in[25];
    const float* img_b = (const float*)d_in[26];
    const float* obj_W = (const float*)d_in[27];
    const float* obj_b = (const float*)d_in[28];

    float* wsp = (float*)d_ws;
    size_t off = 0;
    auto alloc = [&](size_t n) { float* p = wsp + off; off += n; return p; };
    float* rs1  = alloc(B * NV);
    float* rs2  = alloc(B * NO);
    float* sa   = alloc(B * NO);
    float* sbv  = alloc(B * NO);
    float* mr   = alloc(B * NO);
    float* rz   = alloc(B * NO);
    float* s1p  = alloc((size_t)B * CCH * NV);
    float* hv   = alloc((size_t)B * NV * HD);
    float* ho   = alloc((size_t)B * NO * HD);
    float* v1   = alloc((size_t)B * NV * HD);
    float* o1   = alloc((size_t)B * NO * HD);
    float* visb = alloc((size_t)B * NV * HD);
    float* objb = alloc((size_t)B * NO * HD);
    float* cv   = alloc((size_t)B * NV * HD);
    float* co   = alloc((size_t)B * NO * HD);
    float* tmp  = alloc((size_t)B * NO * HD);
    float* accb = alloc((size_t)B * NO * HD);   // shared atomic-accumulate buffer

    colsum_part_k<<<dim3((NV + 255) / 256, CCH, B), 256, 0, stream>>>(A_OV, s1p, B, NO, NV);
    colsum_fin_k<<<dim3((B * NV + 255) / 256), 256, 0, stream>>>(s1p, rs1, B, NV);
    rowsum_inv_k<<<dim3((B * NO + 3) / 4), 256, 0, stream>>>(A_OV, rs1, rs2, B, NO, NV);

    const int vtiles = (NV + ITILE - 1) / ITILE;
    const int otiles = (NO + ITILE - 1) / ITILE;
    auto tps = [](int n) { int tj = (n + JTILE - 1) / JTILE; return (tj + SPLIT - 1) / SPLIT; };
    const int tpsNV = tps(NV), tpsNO = tps(NO);

    auto zero_acc = [&](int rows) {
        hipMemsetAsync(accb, 0, (size_t)rows * HD * sizeof(float), stream);
    };

    auto gat = [&](const float* X, int N, int K, const float* W, const float* a1,
                   const float* a2, const float* adj, float* hbuf, float* outbuf) {
        linear_k<0, 0, 0><<<dim3((B * N + 3) / 4, 1), 128, 0, stream>>>(
            X, W, nullptr, nullptr, hbuf, B * N, K, HD);
        scores_k<<<dim3(B * N), 128, 0, stream>>>(hbuf, a1, a2, sa, sbv, B * N);
        gat_stats_k<<<dim3((B * N + 3) / 4), 256, 0, stream>>>(adj, sa, sbv, mr, rz, B, N);
        int tiles = (N + ITILE - 1) / ITILE;
        zero_acc(B * N);
        gat_agg_k<<<dim3(B * tiles, SPLIT), 128, 0, stream>>>(
            adj, hbuf, sa, sbv, mr, accb, B, N, tps(N));
        finalize_k<1><<<dim3((B * N * (HD / 4) + 255) / 256), 256, 0, stream>>>(
            accb, rz, outbuf, B * N);
    };

    auto cross_and_mlp = [&](const float* vsrc, const float* osrc, float* visout, float* objout) {
        // vis branch: visout = vsrc + mlp(vo @ osrc; o2g)
        zero_acc(B * NV);
        cross_vo_k<<<dim3(B * vtiles, SPLIT), 128, 0, stream>>>(A_OV, osrc, accb, B, NO, NV, tpsNO);
        finalize_k<0><<<dim3((B * NV * (HD / 4) + 255) / 256), 256, 0, stream>>>(
            accb, rs1, cv, B * NV);
        linear_k<1, 1, 0><<<dim3((B * NV + 3) / 4, 1), 128, 0, stream>>>(
            cv, o2g_W1, o2g_b1, nullptr, tmp, B * NV, HD, HD);
        linear_k<0, 1, 1><<<dim3((B * NV + 3) / 4, 1), 128, 0, stream>>>(
            tmp, o2g_W2, o2g_b2, vsrc, visout, B * NV, HD, HD);
        // obj branch: objout = osrc + mlp(ov @ vsrc; g2o)
        zero_acc(B * NO);
        cross_ov_k<<<dim3(B * otiles, SPLIT), 128, 0, stream>>>(A_OV, vsrc, rs1, accb, B, NO, NV, tpsNV);
        finalize_k<0><<<dim3((B * NO * (HD / 4) + 255) / 256), 256, 0, stream>>>(
            accb, rs2, co, B * NO);
        linear_k<1, 1, 0><<<dim3((B * NO + 3) / 4, 1), 128, 0, stream>>>(
            co, g2o_W1, g2o_b1, nullptr, tmp, B * NO, HD, HD);
        linear_k<0, 1, 1><<<dim3((B * NO + 3) / 4, 1), 128, 0, stream>>>(
            tmp, g2o_W2, g2o_b2, osrc, objout, B * NO, HD, HD);
    };

    // layer 1
    gat(vis_memory, NV, DV, Wv1, av1a, av1b, vis_adj, hv, v1);
    gat(obj_memory, NO, DO, Wo1, ao1a, ao1b, obj_adj, ho, o1);
    cross_and_mlp(v1, o1, visb, objb);

    // layer 2
    gat(visb, NV, HD, Wv2, av2a, av2b, vis_adj, hv, v1);
    gat(objb, NO, HD, Wo2, ao2a, ao2b, obj_adj, ho, o1);
    cross_and_mlp(v1, o1, visb, objb);

    // output projections
    float* vis_out = (float*)d_out;
    float* obj_out = vis_out + (size_t)B * NV * DV;
    linear_k<0, 1, 0><<<dim3((B * NV + 3) / 4, (DV + 255) / 256), 128, 0, stream>>>(
        visb, img_W, img_b, nullptr, vis_out, B * NV, HD, DV);
    linear_k<0, 1, 0><<<dim3((B * NO + 3) / 4, 1), 128, 0, stream>>>(
        objb, obj_W, obj_b, nullptr, obj_out, B * NO, HD, DO);
}

// Round 3
// 896.098 us; speedup vs baseline: 2.6626x; 1.9580x over previous
//
#include <hip/hip_runtime.h>
#include <math.h>

#define EPSV 1e-5f
#define HD 128
#define ITILE 32
#define JTILE 32
#define WPAD 33
#define CCH 16

typedef __attribute__((address_space(3))) uint32_t lds_u32_t;
typedef __attribute__((address_space(1))) uint32_t gbl_u32_t;

__device__ __forceinline__ void async_copy16(const float* g, float* l) {
    __builtin_amdgcn_global_load_lds((const gbl_u32_t*)g, (lds_u32_t*)l, 16, 0, 0);
}

// stage a JTILE x HD fp32 tile (16 KB) global -> LDS via async DMA (128 threads)
__device__ __forceinline__ void stage_tile_async(const float* gsrc, float* lds, int t) {
    int wv = t >> 6, lane = t & 63;
    int foff = wv * 256 + lane * 4;
#pragma unroll
    for (int it = 0; it < 8; ++it)
        async_copy16(gsrc + it * 512 + foff, lds + it * 512 + wv * 256);
}

// ---------------- normalization scale kernels ----------------

__global__ void colsum_part_k(const float* __restrict__ A, float* __restrict__ s1p,
                              int B, int NO, int NV) {
    int v = blockIdx.x * 256 + threadIdx.x;
    int c = blockIdx.y, b = blockIdx.z;
    if (v >= NV) return;
    int chunk = (NO + CCH - 1) / CCH;
    int o0 = c * chunk;
    int o1 = o0 + chunk; if (o1 > NO) o1 = NO;
    const float* Ab = A + (size_t)b * NO * NV + v;
    float s = 0.f;
    for (int o = o0; o < o1; ++o) s += Ab[(size_t)o * NV];
    s1p[((size_t)b * CCH + c) * NV + v] = s;
}

__global__ void colsum_fin_k(const float* __restrict__ s1p, float* __restrict__ rs1,
                             int B, int NV) {
    int idx = blockIdx.x * 256 + threadIdx.x;
    if (idx >= B * NV) return;
    int b = idx / NV, v = idx - b * NV;
    float s = 0.f;
    for (int c = 0; c < CCH; ++c) s += s1p[((size_t)b * CCH + c) * NV + v];
    rs1[idx] = 1.f / (s + EPSV);
}

__global__ void rowsum_inv_k(const float* __restrict__ A, const float* __restrict__ rs1,
                             float* __restrict__ rs2, int B, int NO, int NV) {
    int row = blockIdx.x * (blockDim.x >> 6) + (threadIdx.x >> 6);
    int lane = threadIdx.x & 63;
    if (row >= B * NO) return;
    int b = row / NO;
    const float* Ar = A + (size_t)row * NV;
    const float* r1 = rs1 + (size_t)b * NV;
    float s = 0.f;
    for (int v = lane; v < NV; v += 64) s += Ar[v] * r1[v];
    for (int off = 32; off; off >>= 1) s += __shfl_xor(s, off, 64);
    if (lane == 0) rs2[row] = 1.f / (s + EPSV);
}

// ---------------- generic linear: out = act(X@W + bias + res) ----------------
template<int RELU, int BIAS, int RES>
__global__ __launch_bounds__(128)
void linear_k(const float* __restrict__ X, const float* __restrict__ W,
              const float* __restrict__ bias, const float* __restrict__ res,
              float* __restrict__ out, int rows, int K, int Dout) {
    __shared__ float xs[4][512];
    int row0 = blockIdx.x * 4;
    int t = threadIdx.x;
    int K4 = K >> 2;
    for (int l = t; l < 4 * K4; l += 128) {
        int r = l / K4, c4 = l - r * K4;
        float4 val = make_float4(0.f, 0.f, 0.f, 0.f);
        if (row0 + r < rows) val = ((const float4*)(X + (size_t)(row0 + r) * K))[c4];
        ((float4*)&xs[r][0])[c4] = val;
    }
    __syncthreads();
    int chunk = Dout < 256 ? Dout : 256;
    int half = chunk >> 1;
    if (t >= half) return;
    int c0 = blockIdx.y * chunk + t;
    int c1 = c0 + half;
    float a00 = 0, a01 = 0, a02 = 0, a03 = 0, a10 = 0, a11 = 0, a12 = 0, a13 = 0;
#pragma unroll 4
    for (int k = 0; k < K; ++k) {
        float w0 = W[(size_t)k * Dout + c0];
        float w1 = W[(size_t)k * Dout + c1];
        float x0 = xs[0][k], x1 = xs[1][k], x2 = xs[2][k], x3 = xs[3][k];
        a00 = fmaf(x0, w0, a00); a01 = fmaf(x1, w0, a01);
        a02 = fmaf(x2, w0, a02); a03 = fmaf(x3, w0, a03);
        a10 = fmaf(x0, w1, a10); a11 = fmaf(x1, w1, a11);
        a12 = fmaf(x2, w1, a12); a13 = fmaf(x3, w1, a13);
    }
    float accs[2][4] = {{a00, a01, a02, a03}, {a10, a11, a12, a13}};
    int cs[2] = {c0, c1};
    for (int h = 0; h < 2; ++h) {
        float bv = BIAS ? bias[cs[h]] : 0.f;
        for (int r = 0; r < 4; ++r) {
            int row = row0 + r;
            if (row >= rows) continue;
            float v = accs[h][r] + bv;
            if (RES) v += res[(size_t)row * Dout + cs[h]];
            if (RELU) v = fmaxf(v, 0.f);
            out[(size_t)row * Dout + cs[h]] = v;
        }
    }
}

// ---------------- GAT score vectors ----------------
__global__ __launch_bounds__(128)
void scores_k(const float* __restrict__ h, const float* __restrict__ a1,
              const float* __restrict__ a2, float* __restrict__ sa,
              float* __restrict__ sb, int rows) {
    __shared__ float red1[128], red2[128];
    int row = blockIdx.x, t = threadIdx.x;
    float hv = h[(size_t)row * HD + t];
    red1[t] = hv * a1[t];
    red2[t] = hv * a2[t];
    __syncthreads();
    for (int s = 64; s; s >>= 1) {
        if (t < s) { red1[t] += red1[t + s]; red2[t] += red2[t + s]; }
        __syncthreads();
    }
    if (t == 0) { sa[row] = red1[0]; sb[row] = red2[0]; }
}

// per-batch max of sb (lrelu monotone => m_i = lrelu(sa_i + max_j sb_j))
__global__ __launch_bounds__(256)
void sbmax_k(const float* __restrict__ sb, float* __restrict__ sbmax, int N) {
    __shared__ float red[256];
    int b = blockIdx.x, t = threadIdx.x;
    float m = -INFINITY;
    for (int j = t; j < N; j += 256) m = fmaxf(m, sb[(size_t)b * N + j]);
    red[t] = m; __syncthreads();
    for (int s = 128; s; s >>= 1) {
        if (t < s) red[t] = fmaxf(red[t], red[t + s]);
        __syncthreads();
    }
    if (t == 0) sbmax[b] = red[0];
}

// ---------------- shared tile FMA: 4 rows x 8 channels per thread ----------------
__device__ __forceinline__ void tile_fma(const float (*hs)[HD], const float (*ws)[WPAD],
                                         int slot, int c0, float acc[4][8]) {
#pragma unroll 8
    for (int jl = 0; jl < JTILE; ++jl) {
        float4 h0 = *(const float4*)&hs[jl][c0];
        float4 h1 = *(const float4*)&hs[jl][c0 + 64];
#pragma unroll
        for (int q = 0; q < 4; ++q) {
            float w = ws[slot * 4 + q][jl];
            acc[q][0] = fmaf(w, h0.x, acc[q][0]);
            acc[q][1] = fmaf(w, h0.y, acc[q][1]);
            acc[q][2] = fmaf(w, h0.z, acc[q][2]);
            acc[q][3] = fmaf(w, h0.w, acc[q][3]);
            acc[q][4] = fmaf(w, h1.x, acc[q][4]);
            acc[q][5] = fmaf(w, h1.y, acc[q][5]);
            acc[q][6] = fmaf(w, h1.z, acc[q][6]);
            acc[q][7] = fmaf(w, h1.w, acc[q][7]);
        }
    }
}

__device__ __forceinline__ void part_store(float* __restrict__ pp, size_t rowbase,
                                           int i0, int N, int slot, int c0,
                                           float acc[4][8]) {
#pragma unroll
    for (int q = 0; q < 4; ++q) {
        int i = i0 + slot * 4 + q;
        if (i >= N) continue;
        float* op = pp + rowbase + (size_t)i * HD;
        *(float4*)&op[c0]      = make_float4(acc[q][0], acc[q][1], acc[q][2], acc[q][3]);
        *(float4*)&op[c0 + 64] = make_float4(acc[q][4], acc[q][5], acc[q][6], acc[q][7]);
    }
}

// ---------------- GAT aggregation (j-split, partial buffers, inline Z) ----------------
__global__ __launch_bounds__(128)
void gat_agg_k(const float* __restrict__ adj, const float* __restrict__ h,
               const float* __restrict__ sa, const float* __restrict__ sb,
               const float* __restrict__ sbmax, float* __restrict__ ppart,
               float* __restrict__ zpart, int B, int N, int tilesPerSplit) {
    __shared__ float hs[JTILE][HD];
    __shared__ float ws[ITILE][WPAD];
    __shared__ float sa_s[ITILE], m_s[ITILE];
    int tilesPerB = (N + ITILE - 1) / ITILE;
    int b = blockIdx.x / tilesPerB;
    int i0 = (blockIdx.x - b * tilesPerB) * ITILE;
    int split = blockIdx.y;
    int j_begin = split * tilesPerSplit * JTILE;
    if (j_begin >= N) return;
    int j_end = j_begin + tilesPerSplit * JTILE;
    if (j_end > N) j_end = N;
    int t = threadIdx.x;
    if (t < ITILE) {
        int i = i0 + t;
        float s = (i < N) ? sa[(size_t)b * N + i] : 0.f;
        sa_s[t] = s;
        float e = s + sbmax[b];
        m_s[t] = e > 0.f ? e : 0.2f * e;
    }
    int slot = t >> 4, c0 = (t & 15) * 4;
    float acc[4][8];
#pragma unroll
    for (int q = 0; q < 4; ++q)
#pragma unroll
        for (int x = 0; x < 8; ++x) acc[q][x] = 0.f;
    float zacc = 0.f;
    const float* adjb = adj + ((size_t)b * N + i0) * N;
    const float* hb = h + (size_t)b * N * HD;
    const float* sbb = sb + (size_t)b * N;
    __syncthreads();
    for (int j0 = j_begin; j0 < j_end; j0 += JTILE) {
        // async DMA of h tile (overlaps with ws computation below)
        stage_tile_async(hb + (size_t)j0 * HD, &hs[0][0], t);
        // ws: 2 float4 adj loads per thread, w = adj>0 ? exp(lrelu(sa+sb)-m) : 0
#pragma unroll
        for (int k = 0; k < 2; ++k) {
            int l = t + k * 128;
            int il = l >> 3, jl4 = l & 7;
            int i = i0 + il;
            int j = j0 + jl4 * 4;
            float w[4] = {0.f, 0.f, 0.f, 0.f};
            if (i < N && j < N) {
                float sai = sa_s[il], m = m_s[il];
                if (j + 3 < N) {
                    float4 a4 = *(const float4*)&adjb[(size_t)il * N + j];
                    float4 s4 = *(const float4*)&sbb[j];
                    float av[4] = {a4.x, a4.y, a4.z, a4.w};
                    float sv[4] = {s4.x, s4.y, s4.z, s4.w};
#pragma unroll
                    for (int r = 0; r < 4; ++r) {
                        float e = sai + sv[r];
                        e = e > 0.f ? e : 0.2f * e;
                        w[r] = av[r] > 0.f ? __expf(e - m) : 0.f;
                    }
                } else {
#pragma unroll
                    for (int r = 0; r < 4; ++r) {
                        if (j + r < N) {
                            float a = adjb[(size_t)il * N + j + r];
                            float e = sai + sbb[j + r];
                            e = e > 0.f ? e : 0.2f * e;
                            w[r] = a > 0.f ? __expf(e - m) : 0.f;
                        }
                    }
                }
            }
#pragma unroll
            for (int r = 0; r < 4; ++r) ws[il][jl4 * 4 + r] = w[r];
        }
        __syncthreads();
        tile_fma(hs, ws, slot, c0, acc);
        if (t < ITILE) {
            float z = 0.f;
#pragma unroll 8
            for (int jl = 0; jl < JTILE; ++jl) z += ws[t][jl];
            zacc += z;
        }
        __syncthreads();
    }
    size_t rowsTot = (size_t)B * N;
    part_store(ppart, ((size_t)split * rowsTot + (size_t)b * N) * HD, i0, N, slot, c0, acc);
    if (t < ITILE && i0 + t < N)
        zpart[(size_t)split * rowsTot + (size_t)b * N + i0 + t] = zacc;
}

// ---------------- cross vo (out rows = NV, j over NO) ----------------
__global__ __launch_bounds__(128)
void cross_vo_k(const float* __restrict__ A, const float* __restrict__ src,
                float* __restrict__ ppart, int B, int NO, int NV, int tilesPerSplit) {
    __shared__ float hs[JTILE][HD];
    __shared__ float ws[ITILE][WPAD];
    int tilesPerB = (NV + ITILE - 1) / ITILE;
    int b = blockIdx.x / tilesPerB;
    int i0 = (blockIdx.x - b * tilesPerB) * ITILE;
    int split = blockIdx.y;
    int j_begin = split * tilesPerSplit * JTILE;
    if (j_begin >= NO) return;
    int j_end = j_begin + tilesPerSplit * JTILE;
    if (j_end > NO) j_end = NO;
    int t = threadIdx.x;
    int slot = t >> 4, c0 = (t & 15) * 4;
    float acc[4][8];
#pragma unroll
    for (int q = 0; q < 4; ++q)
#pragma unroll
        for (int x = 0; x < 8; ++x) acc[q][x] = 0.f;
    const float* Ab = A + (size_t)b * NO * NV;
    const float* srcb = src + (size_t)b * NO * HD;
    for (int j0 = j_begin; j0 < j_end; j0 += JTILE) {
        stage_tile_async(srcb + (size_t)j0 * HD, &hs[0][0], t);
        for (int l = t; l < ITILE * JTILE; l += 128) {
            int il = l & 31, jl = l >> 5;   // consecutive t -> consecutive v (coalesced)
            int v = i0 + il, o = j0 + jl;
            ws[il][jl] = (v < NV && o < NO) ? Ab[(size_t)o * NV + v] : 0.f;
        }
        __syncthreads();
        tile_fma(hs, ws, slot, c0, acc);
        __syncthreads();
    }
    size_t rowsTot = (size_t)B * NV;
    part_store(ppart, ((size_t)split * rowsTot + (size_t)b * NV) * HD, i0, NV, slot, c0, acc);
}

// ---------------- cross ov (out rows = NO, j over NV; rs1 folded into ws) ----------------
__global__ __launch_bounds__(128)
void cross_ov_k(const float* __restrict__ A, const float* __restrict__ src,
                const float* __restrict__ rs1, float* __restrict__ ppart,
                int B, int NO, int NV, int tilesPerSplit) {
    __shared__ float hs[JTILE][HD];
    __shared__ float ws[ITILE][WPAD];
    int tilesPerB = (NO + ITILE - 1) / ITILE;
    int b = blockIdx.x / tilesPerB;
    int i0 = (blockIdx.x - b * tilesPerB) * ITILE;
    int split = blockIdx.y;
    int j_begin = split * tilesPerSplit * JTILE;
    if (j_begin >= NV) return;
    int j_end = j_begin + tilesPerSplit * JTILE;
    if (j_end > NV) j_end = NV;
    int t = threadIdx.x;
    int slot = t >> 4, c0 = (t & 15) * 4;
    float acc[4][8];
#pragma unroll
    for (int q = 0; q < 4; ++q)
#pragma unroll
        for (int x = 0; x < 8; ++x) acc[q][x] = 0.f;
    const float* Ab = A + (size_t)b * NO * NV;
    const float* srcb = src + (size_t)b * NV * HD;
    const float* r1b = rs1 + (size_t)b * NV;
    for (int j0 = j_begin; j0 < j_end; j0 += JTILE) {
        stage_tile_async(srcb + (size_t)j0 * HD, &hs[0][0], t);
        for (int l = t; l < ITILE * JTILE; l += 128) {
            int il = l >> 5, jl = l & 31;   // consecutive t -> consecutive v (coalesced)
            int o = i0 + il, v = j0 + jl;
            ws[il][jl] = (o < NO && v < NV) ? Ab[(size_t)o * NV + v] * r1b[v] : 0.f;
        }
        __syncthreads();
        tile_fma(hs, ws, slot, c0, acc);
        __syncthreads();
    }
    size_t rowsTot = (size_t)B * NO;
    part_store(ppart, ((size_t)split * rowsTot + (size_t)b * NO) * HD, i0, NO, slot, c0, acc);
}

// ---------------- finalize: sum S partials, scale (1/Z or rs), optional relu --------
template<int ZREL>
__global__ __launch_bounds__(256)
void finalize_part_k(const float* __restrict__ pp, const float* __restrict__ zp,
                     const float* __restrict__ scale, float* __restrict__ out,
                     int rows, int S) {
    int idx = blockIdx.x * 256 + threadIdx.x;
    int total = rows * (HD / 4);
    if (idx >= total) return;
    int row = idx >> 5;
    int c4 = idx & 31;
    float4 v = make_float4(0.f, 0.f, 0.f, 0.f);
    for (int s = 0; s < S; ++s) {
        float4 p = ((const float4*)pp)[((size_t)s * rows + row) * (HD / 4) + c4];
        v.x += p.x; v.y += p.y; v.z += p.z; v.w += p.w;
    }
    float sc;
    if (ZREL) {
        float z = 0.f;
        for (int s = 0; s < S; ++s) z += zp[(size_t)s * rows + row];
        sc = 1.f / z;
    } else {
        sc = scale[row];
    }
    v.x *= sc; v.y *= sc; v.z *= sc; v.w *= sc;
    if (ZREL) {
        v.x = fmaxf(v.x, 0.f); v.y = fmaxf(v.y, 0.f);
        v.z = fmaxf(v.z, 0.f); v.w = fmaxf(v.w, 0.f);
    }
    ((float4*)out)[idx] = v;
}

// ---------------- host launcher ----------------
extern "C" void kernel_launch(void* const* d_in, const int* in_sizes, int n_in,
                              void* d_out, int out_size, void* d_ws, size_t ws_size,
                              hipStream_t stream) {
    const int B = 8, NV = 500, NO = 1500, DV = 512, DO = 32;
    const float* vis_memory = (const float*)d_in[0];
    const float* obj_memory = (const float*)d_in[1];
    const float* vis_adj    = (const float*)d_in[2];
    const float* obj_adj    = (const float*)d_in[3];
    const float* A_OV       = (const float*)d_in[4];
    const float* Wv1  = (const float*)d_in[5];
    const float* av1a = (const float*)d_in[6];
    const float* av1b = (const float*)d_in[7];
    const float* Wv2  = (const float*)d_in[8];
    const float* av2a = (const float*)d_in[9];
    const float* av2b = (const float*)d_in[10];
    const float* Wo1  = (const float*)d_in[11];
    const float* ao1a = (const float*)d_in[12];
    const float* ao1b = (const float*)d_in[13];
    const float* Wo2  = (const float*)d_in[14];
    const float* ao2a = (const float*)d_in[15];
    const float* ao2b = (const float*)d_in[16];
    const float* g2o_W1 = (const float*)d_in[17];
    const float* g2o_b1 = (const float*)d_in[18];
    const float* g2o_W2 = (const float*)d_in[19];
    const float* g2o_b2 = (const float*)d_in[20];
    const float* o2g_W1 = (const float*)d_in[21];
    const float* o2g_b1 = (const float*)d_in[22];
    const float* o2g_W2 = (const float*)d_in[23];
    const float* o2g_b2 = (const float*)d_in[24];
    const float* img_W = (const float*)d_in[25];
    const float* img_b = (const float*)d_in[26];
    const float* obj_W = (const float*)d_in[27];
    const float* obj_b = (const float*)d_in[28];

    float* wsp = (float*)d_ws;
    size_t off = 0;
    auto alloc = [&](size_t n) { float* p = wsp + off; off += n; return p; };
    float* rs1   = alloc(B * NV);
    float* rs2   = alloc(B * NO);
    float* sa    = alloc(B * NO);
    float* sbv   = alloc(B * NO);
    float* sbmax = alloc(B);
    float* s1p   = alloc((size_t)B * CCH * NV);
    float* hv    = alloc((size_t)B * NV * HD);
    float* ho    = alloc((size_t)B * NO * HD);
    float* v1    = alloc((size_t)B * NV * HD);
    float* o1    = alloc((size_t)B * NO * HD);
    float* visb  = alloc((size_t)B * NV * HD);
    float* objb  = alloc((size_t)B * NO * HD);
    float* cv    = alloc((size_t)B * NV * HD);
    float* co    = alloc((size_t)B * NO * HD);
    float* tmp   = alloc((size_t)B * NO * HD);
    float* ppart = alloc((size_t)4 * B * NO * HD);   // max(4*B*NO, 8*B*NV) rows
    float* zpart = alloc((size_t)4 * B * NO);
    alloc(16384);                                     // tail pad for async OOB reads

    colsum_part_k<<<dim3((NV + 255) / 256, CCH, B), 256, 0, stream>>>(A_OV, s1p, B, NO, NV);
    colsum_fin_k<<<dim3((B * NV + 255) / 256), 256, 0, stream>>>(s1p, rs1, B, NV);
    rowsum_inv_k<<<dim3((B * NO + 3) / 4), 256, 0, stream>>>(A_OV, rs1, rs2, B, NO, NV);

    const int vtiles = (NV + ITILE - 1) / ITILE;   // 16
    const int otiles = (NO + ITILE - 1) / ITILE;   // 47
    // split configs: obj-row kernels S=4, vis-row kernels S=8
    const int S_GAT_O = 4, S_GAT_V = 8, S_VO = 8, S_OV = 4;
    auto tps = [](int jtiles, int S) { return (jtiles + S - 1) / S; };

    auto gat = [&](const float* X, int N, int K, const float* W, const float* a1,
                   const float* a2, const float* adj, float* hbuf, float* outbuf) {
        linear_k<0, 0, 0><<<dim3((B * N + 3) / 4, 1), 128, 0, stream>>>(
            X, W, nullptr, nullptr, hbuf, B * N, K, HD);
        scores_k<<<dim3(B * N), 128, 0, stream>>>(hbuf, a1, a2, sa, sbv, B * N);
        sbmax_k<<<dim3(B), 256, 0, stream>>>(sbv, sbmax, N);
        int tiles = (N + ITILE - 1) / ITILE;
        int S = (N == NO) ? S_GAT_O : S_GAT_V;
        gat_agg_k<<<dim3(B * tiles, S), 128, 0, stream>>>(
            adj, hbuf, sa, sbv, sbmax, ppart, zpart, B, N, tps(tiles, S));
        finalize_part_k<1><<<dim3((B * N * (HD / 4) + 255) / 256), 256, 0, stream>>>(
            ppart, zpart, nullptr, outbuf, B * N, S);
    };

    auto cross_and_mlp = [&](const float* vsrc, const float* osrc, float* visout, float* objout) {
        // vis branch: visout = vsrc + mlp(vo @ osrc; o2g)
        cross_vo_k<<<dim3(B * vtiles, S_VO), 128, 0, stream>>>(
            A_OV, osrc, ppart, B, NO, NV, tps(otiles, S_VO));
        finalize_part_k<0><<<dim3((B * NV * (HD / 4) + 255) / 256), 256, 0, stream>>>(
            ppart, nullptr, rs1, cv, B * NV, S_VO);
        linear_k<1, 1, 0><<<dim3((B * NV + 3) / 4, 1), 128, 0, stream>>>(
            cv, o2g_W1, o2g_b1, nullptr, tmp, B * NV, HD, HD);
        linear_k<0, 1, 1><<<dim3((B * NV + 3) / 4, 1), 128, 0, stream>>>(
            tmp, o2g_W2, o2g_b2, vsrc, visout, B * NV, HD, HD);
        // obj branch: objout = osrc + mlp(ov @ vsrc; g2o)
        cross_ov_k<<<dim3(B * otiles, S_OV), 128, 0, stream>>>(
            A_OV, vsrc, rs1, ppart, B, NO, NV, tps(vtiles, S_OV));
        finalize_part_k<0><<<dim3((B * NO * (HD / 4) + 255) / 256), 256, 0, stream>>>(
            ppart, nullptr, rs2, co, B * NO, S_OV);
        linear_k<1, 1, 0><<<dim3((B * NO + 3) / 4, 1), 128, 0, stream>>>(
            co, g2o_W1, g2o_b1, nullptr, tmp, B * NO, HD, HD);
        linear_k<0, 1, 1><<<dim3((B * NO + 3) / 4, 1), 128, 0, stream>>>(
            tmp, g2o_W2, g2o_b2, osrc, objout, B * NO, HD, HD);
    };

    // layer 1
    gat(vis_memory, NV, DV, Wv1, av1a, av1b, vis_adj, hv, v1);
    gat(obj_memory, NO, DO, Wo1, ao1a, ao1b, obj_adj, ho, o1);
    cross_and_mlp(v1, o1, visb, objb);

    // layer 2
    gat(visb, NV, HD, Wv2, av2a, av2b, vis_adj, hv, v1);
    gat(objb, NO, HD, Wo2, ao2a, ao2b, obj_adj, ho, o1);
    cross_and_mlp(v1, o1, visb, objb);

    // output projections
    float* vis_out = (float*)d_out;
    float* obj_out = vis_out + (size_t)B * NV * DV;
    linear_k<0, 1, 0><<<dim3((B * NV + 3) / 4, (DV + 255) / 256), 128, 0, stream>>>(
        visb, img_W, img_b, nullptr, vis_out, B * NV, HD, DV);
    linear_k<0, 1, 0><<<dim3((B * NO + 3) / 4, 1), 128, 0, stream>>>(
        objb, obj_W, obj_b, nullptr, obj_out, B * NO, HD, DO);
}

// Round 4
// 890.826 us; speedup vs baseline: 2.6783x; 1.0059x over previous
//
#include <hip/hip_runtime.h>
#include <math.h>

#define EPSV 1e-5f
#define HD 128
#define IT 64
#define JT 32
#define WP 68
#define CCH 16

typedef __attribute__((address_space(3))) uint32_t lds_u32_t;
typedef __attribute__((address_space(1))) uint32_t gbl_u32_t;

__device__ __forceinline__ void async_copy16(const float* g, float* l) {
    __builtin_amdgcn_global_load_lds((const gbl_u32_t*)g, (lds_u32_t*)l, 16, 0, 0);
}

// stage a JT x HD fp32 tile (16 KB) global -> LDS via async DMA (128 threads)
__device__ __forceinline__ void stage_tile_async(const float* gsrc, float* lds, int t) {
    int wv = t >> 6, lane = t & 63;
    int foff = wv * 256 + lane * 4;
#pragma unroll
    for (int it = 0; it < 8; ++it)
        async_copy16(gsrc + it * 512 + foff, lds + it * 512 + wv * 256);
}

// ---------------- normalization scale kernels ----------------

__global__ void colsum_part_k(const float* __restrict__ A, float* __restrict__ s1p,
                              int B, int NO, int NV) {
    int v = blockIdx.x * 256 + threadIdx.x;
    int c = blockIdx.y, b = blockIdx.z;
    if (v >= NV) return;
    int chunk = (NO + CCH - 1) / CCH;
    int o0 = c * chunk;
    int o1 = o0 + chunk; if (o1 > NO) o1 = NO;
    const float* Ab = A + (size_t)b * NO * NV + v;
    float s = 0.f;
    for (int o = o0; o < o1; ++o) s += Ab[(size_t)o * NV];
    s1p[((size_t)b * CCH + c) * NV + v] = s;
}

__global__ void colsum_fin_k(const float* __restrict__ s1p, float* __restrict__ rs1,
                             int B, int NV) {
    int idx = blockIdx.x * 256 + threadIdx.x;
    if (idx >= B * NV) return;
    int b = idx / NV, v = idx - b * NV;
    float s = 0.f;
    for (int c = 0; c < CCH; ++c) s += s1p[((size_t)b * CCH + c) * NV + v];
    rs1[idx] = 1.f / (s + EPSV);
}

__global__ void rowsum_inv_k(const float* __restrict__ A, const float* __restrict__ rs1,
                             float* __restrict__ rs2, int B, int NO, int NV) {
    int row = blockIdx.x * (blockDim.x >> 6) + (threadIdx.x >> 6);
    int lane = threadIdx.x & 63;
    if (row >= B * NO) return;
    int b = row / NO;
    const float* Ar = A + (size_t)row * NV;
    const float* r1 = rs1 + (size_t)b * NV;
    float s = 0.f;
    for (int v = lane; v < NV; v += 64) s += Ar[v] * r1[v];
    for (int off = 32; off; off >>= 1) s += __shfl_xor(s, off, 64);
    if (lane == 0) rs2[row] = 1.f / (s + EPSV);
}

// ---------------- GAT h-GEMM + fused score vectors ----------------
// 8 rows/block, both waves active: wave w handles rows w*4..w*4+3, channels tt, tt+64.
__global__ __launch_bounds__(128)
void gath_k(const float* __restrict__ X, const float* __restrict__ W,
            const float* __restrict__ a1, const float* __restrict__ a2,
            float* __restrict__ h, float* __restrict__ sa, float* __restrict__ sb,
            int rows, int K) {
    extern __shared__ float xs[];
    int row0 = blockIdx.x * 8;
    int t = threadIdx.x;
    int K4 = K >> 2;
    for (int l = t; l < 8 * K4; l += 128) {
        int r = l / K4, c4 = l - r * K4;
        int row = row0 + r;
        float4 v = make_float4(0.f, 0.f, 0.f, 0.f);
        if (row < rows) v = ((const float4*)(X + (size_t)row * K))[c4];
        ((float4*)&xs[(size_t)r * K])[c4] = v;
    }
    __syncthreads();
    int wv = t >> 6, tt = t & 63, rb = wv * 4;
    float a0[4] = {0.f, 0.f, 0.f, 0.f}, a1v[4] = {0.f, 0.f, 0.f, 0.f};
#pragma unroll 4
    for (int k = 0; k < K; ++k) {
        float w0 = W[(size_t)k * HD + tt];
        float w1 = W[(size_t)k * HD + tt + 64];
#pragma unroll
        for (int r = 0; r < 4; ++r) {
            float x = xs[(size_t)(rb + r) * K + k];
            a0[r] = fmaf(x, w0, a0[r]);
            a1v[r] = fmaf(x, w1, a1v[r]);
        }
    }
    float A1 = a1[tt], A1b = a1[tt + 64], A2 = a2[tt], A2b = a2[tt + 64];
#pragma unroll
    for (int r = 0; r < 4; ++r) {
        int row = row0 + rb + r;
        if (row < rows) {
            h[(size_t)row * HD + tt]      = a0[r];
            h[(size_t)row * HD + tt + 64] = a1v[r];
        }
        float p = a0[r] * A1 + a1v[r] * A1b;
        float q = a0[r] * A2 + a1v[r] * A2b;
#pragma unroll
        for (int off = 32; off; off >>= 1) {
            p += __shfl_xor(p, off, 64);
            q += __shfl_xor(q, off, 64);
        }
        if (tt == 0 && row < rows) { sa[row] = p; sb[row] = q; }
    }
}

// per-batch max of sb (lrelu monotone => m_i = lrelu(sa_i + max_j sb_j))
__global__ __launch_bounds__(256)
void sbmax_k(const float* __restrict__ sb, float* __restrict__ sbmax, int N) {
    __shared__ float red[256];
    int b = blockIdx.x, t = threadIdx.x;
    float m = -INFINITY;
    for (int j = t; j < N; j += 256) m = fmaxf(m, sb[(size_t)b * N + j]);
    red[t] = m; __syncthreads();
    for (int s = 128; s; s >>= 1) {
        if (t < s) red[t] = fmaxf(red[t], red[t + s]);
        __syncthreads();
    }
    if (t == 0) sbmax[b] = red[0];
}

// ---------------- shared tile FMA: 8 rows x 8 channels per thread ----------------
// ws transposed [jl][il], pad 68 so &ws[jl][slot*8] is 16B-aligned -> ds_read_b128
__device__ __forceinline__ void tile_fma64(const float (*hs)[HD], const float (*ws)[WP],
                                           int slot, int c0, float acc[8][8]) {
#pragma unroll 8
    for (int jl = 0; jl < JT; ++jl) {
        float4 h0 = *(const float4*)&hs[jl][c0];
        float4 h1 = *(const float4*)&hs[jl][c0 + 64];
        float4 w0 = *(const float4*)&ws[jl][slot * 8];
        float4 w1 = *(const float4*)&ws[jl][slot * 8 + 4];
        float wq[8] = {w0.x, w0.y, w0.z, w0.w, w1.x, w1.y, w1.z, w1.w};
#pragma unroll
        for (int q = 0; q < 8; ++q) {
            float w = wq[q];
            acc[q][0] = fmaf(w, h0.x, acc[q][0]);
            acc[q][1] = fmaf(w, h0.y, acc[q][1]);
            acc[q][2] = fmaf(w, h0.z, acc[q][2]);
            acc[q][3] = fmaf(w, h0.w, acc[q][3]);
            acc[q][4] = fmaf(w, h1.x, acc[q][4]);
            acc[q][5] = fmaf(w, h1.y, acc[q][5]);
            acc[q][6] = fmaf(w, h1.z, acc[q][6]);
            acc[q][7] = fmaf(w, h1.w, acc[q][7]);
        }
    }
}

__device__ __forceinline__ void part_store64(float* __restrict__ pp, size_t base,
                                             int i0, int N, int slot, int c0,
                                             float acc[8][8]) {
#pragma unroll
    for (int q = 0; q < 8; ++q) {
        int i = i0 + slot * 8 + q;
        if (i >= N) continue;
        float* op = pp + base + (size_t)i * HD;
        *(float4*)&op[c0]      = make_float4(acc[q][0], acc[q][1], acc[q][2], acc[q][3]);
        *(float4*)&op[c0 + 64] = make_float4(acc[q][4], acc[q][5], acc[q][6], acc[q][7]);
    }
}

// ---------------- GAT aggregation (IT=64, j-split partials, inline Z) ----------------
__global__ __launch_bounds__(128)
void gat_agg_k(const float* __restrict__ adj, const float* __restrict__ h,
               const float* __restrict__ sa, const float* __restrict__ sb,
               const float* __restrict__ sbmax, float* __restrict__ ppart,
               float* __restrict__ zpart, int B, int N, int tilesPerSplit) {
    __shared__ float hs[JT][HD];
    __shared__ float ws[JT][WP];
    __shared__ float sa_s[IT], m_s[IT];
    int tilesPerB = (N + IT - 1) / IT;
    int b = blockIdx.x / tilesPerB;
    int i0 = (blockIdx.x - b * tilesPerB) * IT;
    int split = blockIdx.y;
    int j_begin = split * tilesPerSplit * JT;
    if (j_begin >= N) return;
    int j_end = j_begin + tilesPerSplit * JT;
    if (j_end > N) j_end = N;
    int t = threadIdx.x;
    if (t < IT) {
        int i = i0 + t;
        float s = (i < N) ? sa[(size_t)b * N + i] : 0.f;
        sa_s[t] = s;
        float e = s + sbmax[b];
        m_s[t] = e > 0.f ? e : 0.2f * e;
    }
    int slot = t >> 4, c0 = (t & 15) * 4;
    float acc[8][8];
#pragma unroll
    for (int q = 0; q < 8; ++q)
#pragma unroll
        for (int x = 0; x < 8; ++x) acc[q][x] = 0.f;
    float zacc = 0.f;
    const float* adjb = adj + ((size_t)b * N + i0) * N;
    const float* hb = h + (size_t)b * N * HD;
    const float* sbb = sb + (size_t)b * N;
    __syncthreads();
    for (int j0 = j_begin; j0 < j_end; j0 += JT) {
        stage_tile_async(hb + (size_t)j0 * HD, &hs[0][0], t);
        // ws: thread handles (il, jl4): one float4 of adj row il
#pragma unroll
        for (int k = 0; k < 4; ++k) {
            int l = t + k * 128;
            int il = l >> 3, jl4 = l & 7;
            int i = i0 + il;
            int j = j0 + jl4 * 4;
            float w[4] = {0.f, 0.f, 0.f, 0.f};
            if (i < N) {
                float sai = sa_s[il], m = m_s[il];
                if (j + 3 < N) {
                    float4 a4 = *(const float4*)&adjb[(size_t)il * N + j];
                    float4 s4 = *(const float4*)&sbb[j];
                    float av[4] = {a4.x, a4.y, a4.z, a4.w};
                    float sv[4] = {s4.x, s4.y, s4.z, s4.w};
#pragma unroll
                    for (int r = 0; r < 4; ++r) {
                        float e = sai + sv[r];
                        e = e > 0.f ? e : 0.2f * e;
                        w[r] = av[r] > 0.f ? __expf(e - m) : 0.f;
                    }
                } else {
#pragma unroll
                    for (int r = 0; r < 4; ++r) {
                        if (j + r < N) {
                            float a = adjb[(size_t)il * N + j + r];
                            float e = sai + sbb[j + r];
                            e = e > 0.f ? e : 0.2f * e;
                            w[r] = a > 0.f ? __expf(e - m) : 0.f;
                        }
                    }
                }
            }
#pragma unroll
            for (int r = 0; r < 4; ++r) ws[jl4 * 4 + r][il] = w[r];
        }
        __syncthreads();
        tile_fma64(hs, ws, slot, c0, acc);
        if (t < IT) {
            float z = 0.f;
#pragma unroll 8
            for (int jl = 0; jl < JT; ++jl) z += ws[jl][t];
            zacc += z;
        }
        __syncthreads();
    }
    size_t rowsTot = (size_t)B * N;
    part_store64(ppart, ((size_t)split * rowsTot + (size_t)b * N) * HD, i0, N, slot, c0, acc);
    if (t < IT && i0 + t < N)
        zpart[(size_t)split * rowsTot + (size_t)b * N + i0 + t] = zacc;
}

// ---------------- cross vo (out rows = NV, j over NO) ----------------
__global__ __launch_bounds__(128)
void cross_vo_k(const float* __restrict__ A, const float* __restrict__ src,
                float* __restrict__ ppart, int B, int NO, int NV, int tilesPerSplit) {
    __shared__ float hs[JT][HD];
    __shared__ float ws[JT][WP];
    int tilesPerB = (NV + IT - 1) / IT;
    int b = blockIdx.x / tilesPerB;
    int i0 = (blockIdx.x - b * tilesPerB) * IT;
    int split = blockIdx.y;
    int j_begin = split * tilesPerSplit * JT;
    if (j_begin >= NO) return;
    int j_end = j_begin + tilesPerSplit * JT;
    if (j_end > NO) j_end = NO;
    int t = threadIdx.x;
    int slot = t >> 4, c0 = (t & 15) * 4;
    float acc[8][8];
#pragma unroll
    for (int q = 0; q < 8; ++q)
#pragma unroll
        for (int x = 0; x < 8; ++x) acc[q][x] = 0.f;
    const float* Ab = A + (size_t)b * NO * NV;
    const float* srcb = src + (size_t)b * NO * HD;
    for (int j0 = j_begin; j0 < j_end; j0 += JT) {
        stage_tile_async(srcb + (size_t)j0 * HD, &hs[0][0], t);
        // scalar A loads: consecutive t -> consecutive v (coalesced 256B), stores 2-way free
#pragma unroll
        for (int k = 0; k < 16; ++k) {
            int l = t + k * 128;
            int il = l & 63, jl = l >> 6;
            int v = i0 + il, o = j0 + jl;
            ws[jl][il] = (v < NV && o < NO) ? Ab[(size_t)o * NV + v] : 0.f;
        }
        __syncthreads();
        tile_fma64(hs, ws, slot, c0, acc);
        __syncthreads();
    }
    size_t rowsTot = (size_t)B * NV;
    part_store64(ppart, ((size_t)split * rowsTot + (size_t)b * NV) * HD, i0, NV, slot, c0, acc);
}

// ---------------- cross ov (out rows = NO, j over NV; rs1 folded into ws) ----------------
__global__ __launch_bounds__(128)
void cross_ov_k(const float* __restrict__ A, const float* __restrict__ src,
                const float* __restrict__ rs1, float* __restrict__ ppart,
                int B, int NO, int NV, int tilesPerSplit) {
    __shared__ float hs[JT][HD];
    __shared__ float ws[JT][WP];
    int tilesPerB = (NO + IT - 1) / IT;
    int b = blockIdx.x / tilesPerB;
    int i0 = (blockIdx.x - b * tilesPerB) * IT;
    int split = blockIdx.y;
    int j_begin = split * tilesPerSplit * JT;
    if (j_begin >= NV) return;
    int j_end = j_begin + tilesPerSplit * JT;
    if (j_end > NV) j_end = NV;
    int t = threadIdx.x;
    int slot = t >> 4, c0 = (t & 15) * 4;
    float acc[8][8];
#pragma unroll
    for (int q = 0; q < 8; ++q)
#pragma unroll
        for (int x = 0; x < 8; ++x) acc[q][x] = 0.f;
    const float* Ab = A + (size_t)b * NO * NV;
    const float* srcb = src + (size_t)b * NV * HD;
    const float* r1b = rs1 + (size_t)b * NV;
    for (int j0 = j_begin; j0 < j_end; j0 += JT) {
        stage_tile_async(srcb + (size_t)j0 * HD, &hs[0][0], t);
#pragma unroll
        for (int k = 0; k < 4; ++k) {
            int l = t + k * 128;
            int il = l >> 3, jl4 = l & 7;
            int o = i0 + il;
            int v = j0 + jl4 * 4;
            float w[4] = {0.f, 0.f, 0.f, 0.f};
            if (o < NO) {
                if (v + 3 < NV) {
                    float4 a4 = *(const float4*)&Ab[(size_t)o * NV + v];
                    float4 r4 = *(const float4*)&r1b[v];
                    w[0] = a4.x * r4.x; w[1] = a4.y * r4.y;
                    w[2] = a4.z * r4.z; w[3] = a4.w * r4.w;
                } else {
#pragma unroll
                    for (int r = 0; r < 4; ++r)
                        if (v + r < NV) w[r] = Ab[(size_t)o * NV + v + r] * r1b[v + r];
                }
            }
#pragma unroll
            for (int r = 0; r < 4; ++r) ws[jl4 * 4 + r][il] = w[r];
        }
        __syncthreads();
        tile_fma64(hs, ws, slot, c0, acc);
        __syncthreads();
    }
    size_t rowsTot = (size_t)B * NO;
    part_store64(ppart, ((size_t)split * rowsTot + (size_t)b * NO) * HD, i0, NO, slot, c0, acc);
}

// ---------------- finalize GAT: sum S partials, /Z, relu ----------------
__global__ __launch_bounds__(256)
void finalize_gat_k(const float* __restrict__ pp, const float* __restrict__ zp,
                    float* __restrict__ out, int rows, int S) {
    int idx = blockIdx.x * 256 + threadIdx.x;
    int total = rows * (HD / 4);
    if (idx >= total) return;
    int row = idx >> 5;
    float4 v = make_float4(0.f, 0.f, 0.f, 0.f);
    for (int s = 0; s < S; ++s) {
        float4 p = ((const float4*)pp)[((size_t)s * rows + row) * (HD / 4) + (idx & 31)];
        v.x += p.x; v.y += p.y; v.z += p.z; v.w += p.w;
    }
    float z = 0.f;
    for (int s = 0; s < S; ++s) z += zp[(size_t)s * rows + row];
    float sc = 1.f / z;
    v.x = fmaxf(v.x * sc, 0.f); v.y = fmaxf(v.y * sc, 0.f);
    v.z = fmaxf(v.z * sc, 0.f); v.w = fmaxf(v.w * sc, 0.f);
    ((float4*)out)[idx] = v;
}

// ---------------- fused MLP: out = (relu(x@W1+b1))@W2 + b2 + res ----------------
// x = (sum_s ppart slices) * scale[row]. 8 rows/block, both waves active.
__global__ __launch_bounds__(128)
void mlp_k(const float* __restrict__ pp, const float* __restrict__ scale, int S,
           const float* __restrict__ W1, const float* __restrict__ b1,
           const float* __restrict__ W2, const float* __restrict__ b2,
           const float* __restrict__ res, float* __restrict__ out, int rows) {
    __shared__ float xs[8][HD];
    __shared__ float hh[8][HD];
    int row0 = blockIdx.x * 8;
    int t = threadIdx.x;
    for (int l = t; l < 8 * 32; l += 128) {
        int r = l >> 5, c4 = l & 31;
        int row = row0 + r;
        float4 v = make_float4(0.f, 0.f, 0.f, 0.f);
        if (row < rows) {
            for (int s = 0; s < S; ++s) {
                float4 p = ((const float4*)pp)[((size_t)s * rows + row) * 32 + c4];
                v.x += p.x; v.y += p.y; v.z += p.z; v.w += p.w;
            }
            float sc = scale[row];
            v.x *= sc; v.y *= sc; v.z *= sc; v.w *= sc;
        }
        ((float4*)&xs[r][0])[c4] = v;
    }
    __syncthreads();
    int wv = t >> 6, tt = t & 63, rb = wv * 4;
    float a0[4] = {0.f, 0.f, 0.f, 0.f}, a1v[4] = {0.f, 0.f, 0.f, 0.f};
#pragma unroll 4
    for (int k = 0; k < HD; ++k) {
        float w0 = W1[(size_t)k * HD + tt];
        float w1 = W1[(size_t)k * HD + tt + 64];
#pragma unroll
        for (int r = 0; r < 4; ++r) {
            float x = xs[rb + r][k];
            a0[r] = fmaf(x, w0, a0[r]);
            a1v[r] = fmaf(x, w1, a1v[r]);
        }
    }
    float bb0 = b1[tt], bb1 = b1[tt + 64];
#pragma unroll
    for (int r = 0; r < 4; ++r) {
        hh[rb + r][tt]      = fmaxf(a0[r] + bb0, 0.f);
        hh[rb + r][tt + 64] = fmaxf(a1v[r] + bb1, 0.f);
    }
    __syncthreads();
    float c0a[4] = {0.f, 0.f, 0.f, 0.f}, c1a[4] = {0.f, 0.f, 0.f, 0.f};
#pragma unroll 4
    for (int k = 0; k < HD; ++k) {
        float w0 = W2[(size_t)k * HD + tt];
        float w1 = W2[(size_t)k * HD + tt + 64];
#pragma unroll
        for (int r = 0; r < 4; ++r) {
            float x = hh[rb + r][k];
            c0a[r] = fmaf(x, w0, c0a[r]);
            c1a[r] = fmaf(x, w1, c1a[r]);
        }
    }
    float d0 = b2[tt], d1 = b2[tt + 64];
#pragma unroll
    for (int r = 0; r < 4; ++r) {
        int row = row0 + rb + r;
        if (row >= rows) continue;
        out[(size_t)row * HD + tt]      = c0a[r] + d0 + res[(size_t)row * HD + tt];
        out[(size_t)row * HD + tt + 64] = c1a[r] + d1 + res[(size_t)row * HD + tt + 64];
    }
}

// ---------------- output projection (round-3 linear, 4 rows/block) ----------------
template<int RELU, int BIAS, int RES>
__global__ __launch_bounds__(128)
void linear_k(const float* __restrict__ X, const float* __restrict__ W,
              const float* __restrict__ bias, const float* __restrict__ res,
              float* __restrict__ out, int rows, int K, int Dout) {
    __shared__ float xs[4][512];
    int row0 = blockIdx.x * 4;
    int t = threadIdx.x;
    int K4 = K >> 2;
    for (int l = t; l < 4 * K4; l += 128) {
        int r = l / K4, c4 = l - r * K4;
        float4 val = make_float4(0.f, 0.f, 0.f, 0.f);
        if (row0 + r < rows) val = ((const float4*)(X + (size_t)(row0 + r) * K))[c4];
        ((float4*)&xs[r][0])[c4] = val;
    }
    __syncthreads();
    int chunk = Dout < 256 ? Dout : 256;
    int half = chunk >> 1;
    if (t >= half) return;
    int c0 = blockIdx.y * chunk + t;
    int c1 = c0 + half;
    float a00 = 0, a01 = 0, a02 = 0, a03 = 0, a10 = 0, a11 = 0, a12 = 0, a13 = 0;
#pragma unroll 4
    for (int k = 0; k < K; ++k) {
        float w0 = W[(size_t)k * Dout + c0];
        float w1 = W[(size_t)k * Dout + c1];
        float x0 = xs[0][k], x1 = xs[1][k], x2 = xs[2][k], x3 = xs[3][k];
        a00 = fmaf(x0, w0, a00); a01 = fmaf(x1, w0, a01);
        a02 = fmaf(x2, w0, a02); a03 = fmaf(x3, w0, a03);
        a10 = fmaf(x0, w1, a10); a11 = fmaf(x1, w1, a11);
        a12 = fmaf(x2, w1, a12); a13 = fmaf(x3, w1, a13);
    }
    float accs[2][4] = {{a00, a01, a02, a03}, {a10, a11, a12, a13}};
    int cs[2] = {c0, c1};
    for (int h = 0; h < 2; ++h) {
        float bv = BIAS ? bias[cs[h]] : 0.f;
        for (int r = 0; r < 4; ++r) {
            int row = row0 + r;
            if (row >= rows) continue;
            float v = accs[h][r] + bv;
            if (RES) v += res[(size_t)row * Dout + cs[h]];
            if (RELU) v = fmaxf(v, 0.f);
            out[(size_t)row * Dout + cs[h]] = v;
        }
    }
}

// ---------------- host launcher ----------------
extern "C" void kernel_launch(void* const* d_in, const int* in_sizes, int n_in,
                              void* d_out, int out_size, void* d_ws, size_t ws_size,
                              hipStream_t stream) {
    const int B = 8, NV = 500, NO = 1500, DV = 512, DO = 32;
    const float* vis_memory = (const float*)d_in[0];
    const float* obj_memory = (const float*)d_in[1];
    const float* vis_adj    = (const float*)d_in[2];
    const float* obj_adj    = (const float*)d_in[3];
    const float* A_OV       = (const float*)d_in[4];
    const float* Wv1  = (const float*)d_in[5];
    const float* av1a = (const float*)d_in[6];
    const float* av1b = (const float*)d_in[7];
    const float* Wv2  = (const float*)d_in[8];
    const float* av2a = (const float*)d_in[9];
    const float* av2b = (const float*)d_in[10];
    const float* Wo1  = (const float*)d_in[11];
    const float* ao1a = (const float*)d_in[12];
    const float* ao1b = (const float*)d_in[13];
    const float* Wo2  = (const float*)d_in[14];
    const float* ao2a = (const float*)d_in[15];
    const float* ao2b = (const float*)d_in[16];
    const float* g2o_W1 = (const float*)d_in[17];
    const float* g2o_b1 = (const float*)d_in[18];
    const float* g2o_W2 = (const float*)d_in[19];
    const float* g2o_b2 = (const float*)d_in[20];
    const float* o2g_W1 = (const float*)d_in[21];
    const float* o2g_b1 = (const float*)d_in[22];
    const float* o2g_W2 = (const float*)d_in[23];
    const float* o2g_b2 = (const float*)d_in[24];
    const float* img_W = (const float*)d_in[25];
    const float* img_b = (const float*)d_in[26];
    const float* obj_W = (const float*)d_in[27];
    const float* obj_b = (const float*)d_in[28];

    float* wsp = (float*)d_ws;
    size_t off = 0;
    auto alloc = [&](size_t n) { float* p = wsp + off; off += n; return p; };
    float* rs1   = alloc(B * NV);
    float* rs2   = alloc(B * NO);
    float* sa    = alloc(B * NO);
    float* sbv   = alloc(B * NO);
    float* sbmax = alloc(B);
    float* s1p   = alloc((size_t)B * CCH * NV);
    float* hv    = alloc((size_t)B * NV * HD);
    float* ho    = alloc((size_t)B * NO * HD);
    float* v1    = alloc((size_t)B * NV * HD);
    float* o1    = alloc((size_t)B * NO * HD);
    float* visb  = alloc((size_t)B * NV * HD);
    float* objb  = alloc((size_t)B * NO * HD);
    float* ppart = alloc((size_t)8 * B * NO * HD);
    float* zpart = alloc((size_t)8 * B * NO);
    alloc(16384);                                    // tail pad for async OOB reads

    colsum_part_k<<<dim3((NV + 255) / 256, CCH, B), 256, 0, stream>>>(A_OV, s1p, B, NO, NV);
    colsum_fin_k<<<dim3((B * NV + 255) / 256), 256, 0, stream>>>(s1p, rs1, B, NV);
    rowsum_inv_k<<<dim3((B * NO + 3) / 4), 256, 0, stream>>>(A_OV, rs1, rs2, B, NO, NV);

    const int vtiles = (NV + IT - 1) / IT;   // 8
    const int otiles = (NO + IT - 1) / IT;   // 24
    const int S_GAT = 8, S_VO = 8, S_OV = 4;
    auto tps = [](int n, int S) { int tj = (n + JT - 1) / JT; return (tj + S - 1) / S; };
    const int tpsNO8 = tps(NO, 8), tpsNV8 = tps(NV, 8), tpsNV4 = tps(NV, 4);

    auto gat = [&](const float* X, int N, int K, const float* W, const float* a1,
                   const float* a2, const float* adj, float* hbuf, float* outbuf) {
        gath_k<<<dim3(B * N / 8), 128, 8 * K * 4, stream>>>(X, W, a1, a2, hbuf, sa, sbv, B * N, K);
        sbmax_k<<<dim3(B), 256, 0, stream>>>(sbv, sbmax, N);
        int tiles = (N + IT - 1) / IT;
        int tp = (N == NO) ? tpsNO8 : tpsNV8;
        gat_agg_k<<<dim3(B * tiles, S_GAT), 128, 0, stream>>>(
            adj, hbuf, sa, sbv, sbmax, ppart, zpart, B, N, tp);
        finalize_gat_k<<<dim3((B * N * (HD / 4) + 255) / 256), 256, 0, stream>>>(
            ppart, zpart, outbuf, B * N, S_GAT);
    };

    auto cross_and_mlp = [&](const float* vsrc, const float* osrc, float* visout, float* objout) {
        // vis branch: visout = vsrc + mlp(rs1 * (A^T @ osrc); o2g)
        cross_vo_k<<<dim3(B * vtiles, S_VO), 128, 0, stream>>>(A_OV, osrc, ppart, B, NO, NV, tpsNO8);
        mlp_k<<<dim3(B * NV / 8), 128, 0, stream>>>(
            ppart, rs1, S_VO, o2g_W1, o2g_b1, o2g_W2, o2g_b2, vsrc, visout, B * NV);
        // obj branch: objout = osrc + mlp(rs2 * (A @ (rs1*vsrc)); g2o)
        cross_ov_k<<<dim3(B * otiles, S_OV), 128, 0, stream>>>(A_OV, vsrc, rs1, ppart, B, NO, NV, tpsNV4);
        mlp_k<<<dim3(B * NO / 8), 128, 0, stream>>>(
            ppart, rs2, S_OV, g2o_W1, g2o_b1, g2o_W2, g2o_b2, osrc, objout, B * NO);
    };

    // layer 1
    gat(vis_memory, NV, DV, Wv1, av1a, av1b, vis_adj, hv, v1);
    gat(obj_memory, NO, DO, Wo1, ao1a, ao1b, obj_adj, ho, o1);
    cross_and_mlp(v1, o1, visb, objb);

    // layer 2
    gat(visb, NV, HD, Wv2, av2a, av2b, vis_adj, hv, v1);
    gat(objb, NO, HD, Wo2, ao2a, ao2b, obj_adj, ho, o1);
    cross_and_mlp(v1, o1, visb, objb);

    // output projections
    float* vis_out = (float*)d_out;
    float* obj_out = vis_out + (size_t)B * NV * DV;
    linear_k<0, 1, 0><<<dim3((B * NV + 3) / 4, (DV + 255) / 256), 128, 0, stream>>>(
        visb, img_W, img_b, nullptr, vis_out, B * NV, HD, DV);
    linear_k<0, 1, 0><<<dim3((B * NO + 3) / 4, 1), 128, 0, stream>>>(
        objb, obj_W, obj_b, nullptr, obj_out, B * NO, HD, DO);
}

// Round 6
// 787.825 us; speedup vs baseline: 3.0285x; 1.1307x over previous
//
#include <hip/hip_runtime.h>
#include <math.h>

#define EPSV 1e-5f
#define HD 128
#define IT 64
#define JT 32
#define WP 68
#define CCH 16
#define THR 256

typedef __attribute__((address_space(3))) uint32_t lds_u32_t;
typedef __attribute__((address_space(1))) uint32_t gbl_u32_t;

__device__ __forceinline__ void async_copy16(const float* g, float* l) {
    __builtin_amdgcn_global_load_lds((const gbl_u32_t*)g, (lds_u32_t*)l, 16, 0, 0);
}

// stage a JT x HD fp32 tile (16 KB) global -> LDS via async DMA (256 threads)
__device__ __forceinline__ void stage_tile_async(const float* gsrc, float* lds, int t) {
    int wv = t >> 6, lane = t & 63;
#pragma unroll
    for (int it = 0; it < 4; ++it) {
        int c = it * 4 + wv;                    // 1KB chunk per wave-inst
        async_copy16(gsrc + c * 256 + lane * 4, lds + c * 256);
    }
}

// ---------------- normalization scale kernels ----------------

__global__ void colsum_part_k(const float* __restrict__ A, float* __restrict__ s1p,
                              int B, int NO, int NV) {
    int v = blockIdx.x * 256 + threadIdx.x;
    int c = blockIdx.y, b = blockIdx.z;
    if (v >= NV) return;
    int chunk = (NO + CCH - 1) / CCH;
    int o0 = c * chunk;
    int o1 = o0 + chunk; if (o1 > NO) o1 = NO;
    const float* Ab = A + (size_t)b * NO * NV + v;
    float s = 0.f;
    for (int o = o0; o < o1; ++o) s += Ab[(size_t)o * NV];
    s1p[((size_t)b * CCH + c) * NV + v] = s;
}

__global__ void colsum_fin_k(const float* __restrict__ s1p, float* __restrict__ rs1,
                             int B, int NV) {
    int idx = blockIdx.x * 256 + threadIdx.x;
    if (idx >= B * NV) return;
    int b = idx / NV, v = idx - b * NV;
    float s = 0.f;
    for (int c = 0; c < CCH; ++c) s += s1p[((size_t)b * CCH + c) * NV + v];
    rs1[idx] = 1.f / (s + EPSV);
}

__global__ void rowsum_inv_k(const float* __restrict__ A, const float* __restrict__ rs1,
                             float* __restrict__ rs2, int B, int NO, int NV) {
    int row = blockIdx.x * (blockDim.x >> 6) + (threadIdx.x >> 6);
    int lane = threadIdx.x & 63;
    if (row >= B * NO) return;
    int b = row / NO;
    const float* Ar = A + (size_t)row * NV;
    const float* r1 = rs1 + (size_t)b * NV;
    float s = 0.f;
    for (int v = lane; v < NV; v += 64) s += Ar[v] * r1[v];
    for (int off = 32; off; off >>= 1) s += __shfl_xor(s, off, 64);
    if (lane == 0) rs2[row] = 1.f / (s + EPSV);
}

// ---------------- GAT h-GEMM + fused score vectors ----------------
__global__ __launch_bounds__(128)
void gath_k(const float* __restrict__ X, const float* __restrict__ W,
            const float* __restrict__ a1, const float* __restrict__ a2,
            float* __restrict__ h, float* __restrict__ sa, float* __restrict__ sb,
            int rows, int K) {
    extern __shared__ float xs[];
    int row0 = blockIdx.x * 8;
    int t = threadIdx.x;
    int K4 = K >> 2;
    for (int l = t; l < 8 * K4; l += 128) {
        int r = l / K4, c4 = l - r * K4;
        int row = row0 + r;
        float4 v = make_float4(0.f, 0.f, 0.f, 0.f);
        if (row < rows) v = ((const float4*)(X + (size_t)row * K))[c4];
        ((float4*)&xs[(size_t)r * K])[c4] = v;
    }
    __syncthreads();
    int wv = t >> 6, tt = t & 63, rb = wv * 4;
    float a0[4] = {0.f, 0.f, 0.f, 0.f}, a1v[4] = {0.f, 0.f, 0.f, 0.f};
#pragma unroll 4
    for (int k = 0; k < K; ++k) {
        float w0 = W[(size_t)k * HD + tt];
        float w1 = W[(size_t)k * HD + tt + 64];
#pragma unroll
        for (int r = 0; r < 4; ++r) {
            float x = xs[(size_t)(rb + r) * K + k];
            a0[r] = fmaf(x, w0, a0[r]);
            a1v[r] = fmaf(x, w1, a1v[r]);
        }
    }
    float A1 = a1[tt], A1b = a1[tt + 64], A2 = a2[tt], A2b = a2[tt + 64];
#pragma unroll
    for (int r = 0; r < 4; ++r) {
        int row = row0 + rb + r;
        if (row < rows) {
            h[(size_t)row * HD + tt]      = a0[r];
            h[(size_t)row * HD + tt + 64] = a1v[r];
        }
        float p = a0[r] * A1 + a1v[r] * A1b;
        float q = a0[r] * A2 + a1v[r] * A2b;
#pragma unroll
        for (int off = 32; off; off >>= 1) {
            p += __shfl_xor(p, off, 64);
            q += __shfl_xor(q, off, 64);
        }
        if (tt == 0 && row < rows) { sa[row] = p; sb[row] = q; }
    }
}

__global__ __launch_bounds__(256)
void sbmax_k(const float* __restrict__ sb, float* __restrict__ sbmax, int N) {
    __shared__ float red[256];
    int b = blockIdx.x, t = threadIdx.x;
    float m = -INFINITY;
    for (int j = t; j < N; j += 256) m = fmaxf(m, sb[(size_t)b * N + j]);
    red[t] = m; __syncthreads();
    for (int s = 128; s; s >>= 1) {
        if (t < s) red[t] = fmaxf(red[t], red[t + s]);
        __syncthreads();
    }
    if (t == 0) sbmax[b] = red[0];
}

// ---------------- 256-thread tile FMA: 4 rows x 8 channels per thread ----------------
__device__ __forceinline__ void tile_fma256(const float (*hs)[HD], const float (*ws)[WP],
                                            int rg, int c0, float acc[4][8]) {
#pragma unroll 8
    for (int jl = 0; jl < JT; ++jl) {
        float4 h0 = *(const float4*)&hs[jl][c0];
        float4 h1 = *(const float4*)&hs[jl][c0 + 64];
        float4 w4 = *(const float4*)&ws[jl][rg * 4];
        float wq[4] = {w4.x, w4.y, w4.z, w4.w};
#pragma unroll
        for (int q = 0; q < 4; ++q) {
            float w = wq[q];
            acc[q][0] = fmaf(w, h0.x, acc[q][0]);
            acc[q][1] = fmaf(w, h0.y, acc[q][1]);
            acc[q][2] = fmaf(w, h0.z, acc[q][2]);
            acc[q][3] = fmaf(w, h0.w, acc[q][3]);
            acc[q][4] = fmaf(w, h1.x, acc[q][4]);
            acc[q][5] = fmaf(w, h1.y, acc[q][5]);
            acc[q][6] = fmaf(w, h1.z, acc[q][6]);
            acc[q][7] = fmaf(w, h1.w, acc[q][7]);
        }
    }
}

__device__ __forceinline__ void part_store256(float* __restrict__ pp, size_t base,
                                              int i0, int N, int rg, int c0,
                                              float acc[4][8]) {
#pragma unroll
    for (int q = 0; q < 4; ++q) {
        int i = i0 + rg * 4 + q;
        if (i >= N) continue;
        float* op = pp + base + (size_t)i * HD;
        *(float4*)&op[c0]      = make_float4(acc[q][0], acc[q][1], acc[q][2], acc[q][3]);
        *(float4*)&op[c0 + 64] = make_float4(acc[q][4], acc[q][5], acc[q][6], acc[q][7]);
    }
}

// ---------------- GAT aggregation: pipelined, 1 barrier/tile ----------------
__global__ __launch_bounds__(256)
void gat_agg_k(const float* __restrict__ adj, const float* __restrict__ h,
               const float* __restrict__ sa, const float* __restrict__ sb,
               const float* __restrict__ sbmax, float* __restrict__ ppart,
               float* __restrict__ zpart, int B, int N, int tilesPerSplit) {
    __shared__ float hs[2][JT][HD];
    __shared__ float ws[2][JT][WP];
    __shared__ float sa_s[IT], m_s[IT];
    int tilesPerB = (N + IT - 1) / IT;
    int b = blockIdx.x / tilesPerB;
    int i0 = (blockIdx.x - b * tilesPerB) * IT;
    int split = blockIdx.y;
    int j_begin = split * tilesPerSplit * JT;
    if (j_begin >= N) return;
    int j_end = j_begin + tilesPerSplit * JT;
    if (j_end > N) j_end = N;
    int T = (j_end - j_begin + JT - 1) / JT;
    int t = threadIdx.x;
    if (t < IT) {
        int i = i0 + t;
        float s = (i < N) ? sa[(size_t)b * N + i] : 0.f;
        sa_s[t] = s;
        float e = s + sbmax[b];
        m_s[t] = e > 0.f ? e : 0.2f * e;
    }
    __syncthreads();   // sa_s/m_s visible to ALL waves before first ws computation
    int rg = t >> 4, c0 = (t & 15) * 4;
    int il = t >> 2, j4 = (t & 3) * 4;
    float acc[4][8];
#pragma unroll
    for (int q = 0; q < 4; ++q)
#pragma unroll
        for (int x = 0; x < 8; ++x) acc[q][x] = 0.f;
    float zacc = 0.f;
    const float* adjb = adj + ((size_t)b * N + i0) * N;
    const float* hb = h + (size_t)b * N * HD;
    const float* sbb = sb + (size_t)b * N;
    int irow = i0 + il;
    // prologue: DMA tile0 + adj regs tile0
    stage_tile_async(hb + (size_t)j_begin * HD, &hs[0][0][0], t);
    float4 a4[2], s4[2];
#pragma unroll
    for (int k = 0; k < 2; ++k) {
        int j = j_begin + j4 + k * 16;
        bool ok = (irow < N) && (j < N);
        a4[k] = ok ? *(const float4*)&adjb[(size_t)il * N + j] : make_float4(0.f,0.f,0.f,0.f);
        s4[k] = ok ? *(const float4*)&sbb[j] : make_float4(0.f,0.f,0.f,0.f);
    }
    for (int tt = 0; tt < T; ++tt) {
        int cur = tt & 1;
        // write ws[cur] from prefetched regs
        float sai = sa_s[il], m = m_s[il];
#pragma unroll
        for (int k = 0; k < 2; ++k) {
            float av[4] = {a4[k].x, a4[k].y, a4[k].z, a4[k].w};
            float sv[4] = {s4[k].x, s4[k].y, s4[k].z, s4[k].w};
#pragma unroll
            for (int r = 0; r < 4; ++r) {
                float e = sai + sv[r];
                e = e > 0.f ? e : 0.2f * e;
                ws[cur][j4 + r + k * 16][il] = av[r] > 0.f ? __expf(e - m) : 0.f;
            }
        }
        __syncthreads();   // ws[cur] visible; hs[cur] DMA drained
        if (tt + 1 < T) {
            int jn = j_begin + (tt + 1) * JT;
            stage_tile_async(hb + (size_t)jn * HD, &hs[1 - cur][0][0], t);
#pragma unroll
            for (int k = 0; k < 2; ++k) {
                int j = jn + j4 + k * 16;
                bool ok = (irow < N) && (j < N);
                a4[k] = ok ? *(const float4*)&adjb[(size_t)il * N + j] : make_float4(0.f,0.f,0.f,0.f);
                s4[k] = ok ? *(const float4*)&sbb[j] : make_float4(0.f,0.f,0.f,0.f);
            }
        }
        tile_fma256(hs[cur], ws[cur], rg, c0, acc);
        if (t < IT) {
            float z = 0.f;
#pragma unroll 8
            for (int jl = 0; jl < JT; ++jl) z += ws[cur][jl][t];
            zacc += z;
        }
    }
    size_t rowsTot = (size_t)B * N;
    part_store256(ppart, ((size_t)split * rowsTot + (size_t)b * N) * HD, i0, N, rg, c0, acc);
    if (t < IT && i0 + t < N)
        zpart[(size_t)split * rowsTot + (size_t)b * N + i0 + t] = zacc;
}

// ---------------- cross vo: pipelined (out rows = NV, j over NO) ----------------
__global__ __launch_bounds__(256)
void cross_vo_k(const float* __restrict__ A, const float* __restrict__ src,
                float* __restrict__ ppart, int B, int NO, int NV, int tilesPerSplit) {
    __shared__ float hs[2][JT][HD];
    __shared__ float ws[2][JT][WP];
    int tilesPerB = (NV + IT - 1) / IT;
    int b = blockIdx.x / tilesPerB;
    int i0 = (blockIdx.x - b * tilesPerB) * IT;
    int split = blockIdx.y;
    int j_begin = split * tilesPerSplit * JT;
    if (j_begin >= NO) return;
    int j_end = j_begin + tilesPerSplit * JT;
    if (j_end > NO) j_end = NO;
    int T = (j_end - j_begin + JT - 1) / JT;
    int t = threadIdx.x;
    int rg = t >> 4, c0 = (t & 15) * 4;
    int il = t & 63, jlb = t >> 6;          // thread owns column v=i0+il, rows jlb+4k
    float acc[4][8];
#pragma unroll
    for (int q = 0; q < 4; ++q)
#pragma unroll
        for (int x = 0; x < 8; ++x) acc[q][x] = 0.f;
    const float* Ab = A + (size_t)b * NO * NV;
    const float* srcb = src + (size_t)b * NO * HD;
    int v = i0 + il;
    float w8[8];
    stage_tile_async(srcb + (size_t)j_begin * HD, &hs[0][0][0], t);
#pragma unroll
    for (int k = 0; k < 8; ++k) {
        int o = j_begin + jlb + k * 4;
        w8[k] = (v < NV && o < NO) ? Ab[(size_t)o * NV + v] : 0.f;
    }
    for (int tt = 0; tt < T; ++tt) {
        int cur = tt & 1;
#pragma unroll
        for (int k = 0; k < 8; ++k) ws[cur][jlb + k * 4][il] = w8[k];
        __syncthreads();
        if (tt + 1 < T) {
            int jn = j_begin + (tt + 1) * JT;
            stage_tile_async(srcb + (size_t)jn * HD, &hs[1 - cur][0][0], t);
#pragma unroll
            for (int k = 0; k < 8; ++k) {
                int o = jn + jlb + k * 4;
                w8[k] = (v < NV && o < NO) ? Ab[(size_t)o * NV + v] : 0.f;
            }
        }
        tile_fma256(hs[cur], ws[cur], rg, c0, acc);
    }
    size_t rowsTot = (size_t)B * NV;
    part_store256(ppart, ((size_t)split * rowsTot + (size_t)b * NV) * HD, i0, NV, rg, c0, acc);
}

// ---------------- cross ov: pipelined (out rows = NO, j over NV; rs1 folded) --------
__global__ __launch_bounds__(256)
void cross_ov_k(const float* __restrict__ A, const float* __restrict__ src,
                const float* __restrict__ rs1, float* __restrict__ ppart,
                int B, int NO, int NV, int tilesPerSplit) {
    __shared__ float hs[2][JT][HD];
    __shared__ float ws[2][JT][WP];
    int tilesPerB = (NO + IT - 1) / IT;
    int b = blockIdx.x / tilesPerB;
    int i0 = (blockIdx.x - b * tilesPerB) * IT;
    int split = blockIdx.y;
    int j_begin = split * tilesPerSplit * JT;
    if (j_begin >= NV) return;
    int j_end = j_begin + tilesPerSplit * JT;
    if (j_end > NV) j_end = NV;
    int T = (j_end - j_begin + JT - 1) / JT;
    int t = threadIdx.x;
    int rg = t >> 4, c0 = (t & 15) * 4;
    int il = t >> 2, j4 = (t & 3) * 4;
    float acc[4][8];
#pragma unroll
    for (int q = 0; q < 4; ++q)
#pragma unroll
        for (int x = 0; x < 8; ++x) acc[q][x] = 0.f;
    const float* Ab = A + (size_t)b * NO * NV;
    const float* srcb = src + (size_t)b * NV * HD;
    const float* r1b = rs1 + (size_t)b * NV;
    int orow = i0 + il;
    float4 a4[2], r4[2];
    stage_tile_async(srcb + (size_t)j_begin * HD, &hs[0][0][0], t);
#pragma unroll
    for (int k = 0; k < 2; ++k) {
        int vv = j_begin + j4 + k * 16;
        bool ok = (orow < NO) && (vv < NV);
        a4[k] = ok ? *(const float4*)&Ab[(size_t)orow * NV + vv] : make_float4(0.f,0.f,0.f,0.f);
        r4[k] = ok ? *(const float4*)&r1b[vv] : make_float4(0.f,0.f,0.f,0.f);
    }
    for (int tt = 0; tt < T; ++tt) {
        int cur = tt & 1;
#pragma unroll
        for (int k = 0; k < 2; ++k) {
            float wv[4] = {a4[k].x * r4[k].x, a4[k].y * r4[k].y,
                           a4[k].z * r4[k].z, a4[k].w * r4[k].w};
#pragma unroll
            for (int r = 0; r < 4; ++r) ws[cur][j4 + r + k * 16][il] = wv[r];
        }
        __syncthreads();
        if (tt + 1 < T) {
            int jn = j_begin + (tt + 1) * JT;
            stage_tile_async(srcb + (size_t)jn * HD, &hs[1 - cur][0][0], t);
#pragma unroll
            for (int k = 0; k < 2; ++k) {
                int vv = jn + j4 + k * 16;
                bool ok = (orow < NO) && (vv < NV);
                a4[k] = ok ? *(const float4*)&Ab[(size_t)orow * NV + vv] : make_float4(0.f,0.f,0.f,0.f);
                r4[k] = ok ? *(const float4*)&r1b[vv] : make_float4(0.f,0.f,0.f,0.f);
            }
        }
        tile_fma256(hs[cur], ws[cur], rg, c0, acc);
    }
    size_t rowsTot = (size_t)B * NO;
    part_store256(ppart, ((size_t)split * rowsTot + (size_t)b * NO) * HD, i0, NO, rg, c0, acc);
}

// ---------------- finalize GAT: sum S partials, /Z, relu ----------------
__global__ __launch_bounds__(256)
void finalize_gat_k(const float* __restrict__ pp, const float* __restrict__ zp,
                    float* __restrict__ out, int rows, int S) {
    int idx = blockIdx.x * 256 + threadIdx.x;
    int total = rows * (HD / 4);
    if (idx >= total) return;
    int row = idx >> 5;
    float4 v = make_float4(0.f, 0.f, 0.f, 0.f);
    for (int s = 0; s < S; ++s) {
        float4 p = ((const float4*)pp)[((size_t)s * rows + row) * (HD / 4) + (idx & 31)];
        v.x += p.x; v.y += p.y; v.z += p.z; v.w += p.w;
    }
    float z = 0.f;
    for (int s = 0; s < S; ++s) z += zp[(size_t)s * rows + row];
    float sc = 1.f / z;
    v.x = fmaxf(v.x * sc, 0.f); v.y = fmaxf(v.y * sc, 0.f);
    v.z = fmaxf(v.z * sc, 0.f); v.w = fmaxf(v.w * sc, 0.f);
    ((float4*)out)[idx] = v;
}

// ---------------- fused MLP: out = (relu(x@W1+b1))@W2 + b2 + res ----------------
__global__ __launch_bounds__(128)
void mlp_k(const float* __restrict__ pp, const float* __restrict__ scale, int S,
           const float* __restrict__ W1, const float* __restrict__ b1,
           const float* __restrict__ W2, const float* __restrict__ b2,
           const float* __restrict__ res, float* __restrict__ out, int rows) {
    __shared__ float xs[8][HD];
    __shared__ float hh[8][HD];
    int row0 = blockIdx.x * 8;
    int t = threadIdx.x;
    for (int l = t; l < 8 * 32; l += 128) {
        int r = l >> 5, c4 = l & 31;
        int row = row0 + r;
        float4 v = make_float4(0.f, 0.f, 0.f, 0.f);
        if (row < rows) {
            for (int s = 0; s < S; ++s) {
                float4 p = ((const float4*)pp)[((size_t)s * rows + row) * 32 + c4];
                v.x += p.x; v.y += p.y; v.z += p.z; v.w += p.w;
            }
            float sc = scale[row];
            v.x *= sc; v.y *= sc; v.z *= sc; v.w *= sc;
        }
        ((float4*)&xs[r][0])[c4] = v;
    }
    __syncthreads();
    int wv = t >> 6, tt = t & 63, rb = wv * 4;
    float a0[4] = {0.f, 0.f, 0.f, 0.f}, a1v[4] = {0.f, 0.f, 0.f, 0.f};
#pragma unroll 4
    for (int k = 0; k < HD; ++k) {
        float w0 = W1[(size_t)k * HD + tt];
        float w1 = W1[(size_t)k * HD + tt + 64];
#pragma unroll
        for (int r = 0; r < 4; ++r) {
            float x = xs[rb + r][k];
            a0[r] = fmaf(x, w0, a0[r]);
            a1v[r] = fmaf(x, w1, a1v[r]);
        }
    }
    float bb0 = b1[tt], bb1 = b1[tt + 64];
#pragma unroll
    for (int r = 0; r < 4; ++r) {
        hh[rb + r][tt]      = fmaxf(a0[r] + bb0, 0.f);
        hh[rb + r][tt + 64] = fmaxf(a1v[r] + bb1, 0.f);
    }
    __syncthreads();
    float c0a[4] = {0.f, 0.f, 0.f, 0.f}, c1a[4] = {0.f, 0.f, 0.f, 0.f};
#pragma unroll 4
    for (int k = 0; k < HD; ++k) {
        float w0 = W2[(size_t)k * HD + tt];
        float w1 = W2[(size_t)k * HD + tt + 64];
#pragma unroll
        for (int r = 0; r < 4; ++r) {
            float x = hh[rb + r][k];
            c0a[r] = fmaf(x, w0, c0a[r]);
            c1a[r] = fmaf(x, w1, c1a[r]);
        }
    }
    float d0 = b2[tt], d1 = b2[tt + 64];
#pragma unroll
    for (int r = 0; r < 4; ++r) {
        int row = row0 + rb + r;
        if (row >= rows) continue;
        out[(size_t)row * HD + tt]      = c0a[r] + d0 + res[(size_t)row * HD + tt];
        out[(size_t)row * HD + tt + 64] = c1a[r] + d1 + res[(size_t)row * HD + tt + 64];
    }
}

// ---------------- output projection ----------------
template<int RELU, int BIAS, int RES>
__global__ __launch_bounds__(128)
void linear_k(const float* __restrict__ X, const float* __restrict__ W,
              const float* __restrict__ bias, const float* __restrict__ res,
              float* __restrict__ out, int rows, int K, int Dout) {
    __shared__ float xs[4][512];
    int row0 = blockIdx.x * 4;
    int t = threadIdx.x;
    int K4 = K >> 2;
    for (int l = t; l < 4 * K4; l += 128) {
        int r = l / K4, c4 = l - r * K4;
        float4 val = make_float4(0.f, 0.f, 0.f, 0.f);
        if (row0 + r < rows) val = ((const float4*)(X + (size_t)(row0 + r) * K))[c4];
        ((float4*)&xs[r][0])[c4] = val;
    }
    __syncthreads();
    int chunk = Dout < 256 ? Dout : 256;
    int half = chunk >> 1;
    if (t >= half) return;
    int c0 = blockIdx.y * chunk + t;
    int c1 = c0 + half;
    float a00 = 0, a01 = 0, a02 = 0, a03 = 0, a10 = 0, a11 = 0, a12 = 0, a13 = 0;
#pragma unroll 4
    for (int k = 0; k < K; ++k) {
        float w0 = W[(size_t)k * Dout + c0];
        float w1 = W[(size_t)k * Dout + c1];
        float x0 = xs[0][k], x1 = xs[1][k], x2 = xs[2][k], x3 = xs[3][k];
        a00 = fmaf(x0, w0, a00); a01 = fmaf(x1, w0, a01);
        a02 = fmaf(x2, w0, a02); a03 = fmaf(x3, w0, a03);
        a10 = fmaf(x0, w1, a10); a11 = fmaf(x1, w1, a11);
        a12 = fmaf(x2, w1, a12); a13 = fmaf(x3, w1, a13);
    }
    float accs[2][4] = {{a00, a01, a02, a03}, {a10, a11, a12, a13}};
    int cs[2] = {c0, c1};
    for (int h = 0; h < 2; ++h) {
        float bv = BIAS ? bias[cs[h]] : 0.f;
        for (int r = 0; r < 4; ++r) {
            int row = row0 + r;
            if (row >= rows) continue;
            float v = accs[h][r] + bv;
            if (RES) v += res[(size_t)row * Dout + cs[h]];
            if (RELU) v = fmaxf(v, 0.f);
            out[(size_t)row * Dout + cs[h]] = v;
        }
    }
}

// ---------------- host launcher ----------------
extern "C" void kernel_launch(void* const* d_in, const int* in_sizes, int n_in,
                              void* d_out, int out_size, void* d_ws, size_t ws_size,
                              hipStream_t stream) {
    const int B = 8, NV = 500, NO = 1500, DV = 512, DO = 32;
    const float* vis_memory = (const float*)d_in[0];
    const float* obj_memory = (const float*)d_in[1];
    const float* vis_adj    = (const float*)d_in[2];
    const float* obj_adj    = (const float*)d_in[3];
    const float* A_OV       = (const float*)d_in[4];
    const float* Wv1  = (const float*)d_in[5];
    const float* av1a = (const float*)d_in[6];
    const float* av1b = (const float*)d_in[7];
    const float* Wv2  = (const float*)d_in[8];
    const float* av2a = (const float*)d_in[9];
    const float* av2b = (const float*)d_in[10];
    const float* Wo1  = (const float*)d_in[11];
    const float* ao1a = (const float*)d_in[12];
    const float* ao1b = (const float*)d_in[13];
    const float* Wo2  = (const float*)d_in[14];
    const float* ao2a = (const float*)d_in[15];
    const float* ao2b = (const float*)d_in[16];
    const float* g2o_W1 = (const float*)d_in[17];
    const float* g2o_b1 = (const float*)d_in[18];
    const float* g2o_W2 = (const float*)d_in[19];
    const float* g2o_b2 = (const float*)d_in[20];
    const float* o2g_W1 = (const float*)d_in[21];
    const float* o2g_b1 = (const float*)d_in[22];
    const float* o2g_W2 = (const float*)d_in[23];
    const float* o2g_b2 = (const float*)d_in[24];
    const float* img_W = (const float*)d_in[25];
    const float* img_b = (const float*)d_in[26];
    const float* obj_W = (const float*)d_in[27];
    const float* obj_b = (const float*)d_in[28];

    float* wsp = (float*)d_ws;
    size_t off = 0;
    auto alloc = [&](size_t n) { float* p = wsp + off; off += n; return p; };
    float* rs1   = alloc(B * NV);
    float* rs2   = alloc(B * NO);
    float* sa    = alloc(B * NO);
    float* sbv   = alloc(B * NO);
    float* sbmax = alloc(B);
    float* s1p   = alloc((size_t)B * CCH * NV);
    float* hv    = alloc((size_t)B * NV * HD);
    float* ho    = alloc((size_t)B * NO * HD);
    float* v1    = alloc((size_t)B * NV * HD);
    float* o1    = alloc((size_t)B * NO * HD);
    float* visb  = alloc((size_t)B * NV * HD);
    float* objb  = alloc((size_t)B * NO * HD);
    float* ppart = alloc((size_t)8 * B * NO * HD);
    float* zpart = alloc((size_t)8 * B * NO);
    alloc(16384);                                    // tail pad for async OOB reads

    colsum_part_k<<<dim3((NV + 255) / 256, CCH, B), 256, 0, stream>>>(A_OV, s1p, B, NO, NV);
    colsum_fin_k<<<dim3((B * NV + 255) / 256), 256, 0, stream>>>(s1p, rs1, B, NV);
    rowsum_inv_k<<<dim3((B * NO + 3) / 4), 256, 0, stream>>>(A_OV, rs1, rs2, B, NO, NV);

    const int vtiles = (NV + IT - 1) / IT;   // 8
    const int otiles = (NO + IT - 1) / IT;   // 24
    const int S_GAT_O = 4, S_GAT_V = 8, S_VO = 8, S_OV = 4;
    auto tps = [](int n, int S) { int tj = (n + JT - 1) / JT; return (tj + S - 1) / S; };

    auto gat = [&](const float* X, int N, int K, const float* W, const float* a1,
                   const float* a2, const float* adj, float* hbuf, float* outbuf) {
        gath_k<<<dim3(B * N / 8), 128, 8 * K * 4, stream>>>(X, W, a1, a2, hbuf, sa, sbv, B * N, K);
        sbmax_k<<<dim3(B), 256, 0, stream>>>(sbv, sbmax, N);
        int tiles = (N + IT - 1) / IT;
        int S = (N == NO) ? S_GAT_O : S_GAT_V;
        gat_agg_k<<<dim3(B * tiles, S), THR, 0, stream>>>(
            adj, hbuf, sa, sbv, sbmax, ppart, zpart, B, N, tps(N, S));
        finalize_gat_k<<<dim3((B * N * (HD / 4) + 255) / 256), 256, 0, stream>>>(
            ppart, zpart, outbuf, B * N, S);
    };

    auto cross_and_mlp = [&](const float* vsrc, const float* osrc, float* visout, float* objout) {
        cross_vo_k<<<dim3(B * vtiles, S_VO), THR, 0, stream>>>(
            A_OV, osrc, ppart, B, NO, NV, tps(NO, S_VO));
        mlp_k<<<dim3(B * NV / 8), 128, 0, stream>>>(
            ppart, rs1, S_VO, o2g_W1, o2g_b1, o2g_W2, o2g_b2, vsrc, visout, B * NV);
        cross_ov_k<<<dim3(B * otiles, S_OV), THR, 0, stream>>>(
            A_OV, vsrc, rs1, ppart, B, NO, NV, tps(NV, S_OV));
        mlp_k<<<dim3(B * NO / 8), 128, 0, stream>>>(
            ppart, rs2, S_OV, g2o_W1, g2o_b1, g2o_W2, g2o_b2, osrc, objout, B * NO);
    };

    // layer 1
    gat(vis_memory, NV, DV, Wv1, av1a, av1b, vis_adj, hv, v1);
    gat(obj_memory, NO, DO, Wo1, ao1a, ao1b, obj_adj, ho, o1);
    cross_and_mlp(v1, o1, visb, objb);

    // layer 2
    gat(visb, NV, HD, Wv2, av2a, av2b, vis_adj, hv, v1);
    gat(objb, NO, HD, Wo2, ao2a, ao2b, obj_adj, ho, o1);
    cross_and_mlp(v1, o1, visb, objb);

    // output projections
    float* vis_out = (float*)d_out;
    float* obj_out = vis_out + (size_t)B * NV * DV;
    linear_k<0, 1, 0><<<dim3((B * NV + 3) / 4, (DV + 255) / 256), 128, 0, stream>>>(
        visb, img_W, img_b, nullptr, vis_out, B * NV, HD, DV);
    linear_k<0, 1, 0><<<dim3((B * NO + 3) / 4, 1), 128, 0, stream>>>(
        objb, obj_W, obj_b, nullptr, obj_out, B * NO, HD, DO);
}